// Round 10
// baseline (1730.200 us; speedup 1.0000x reference)
//
#include <hip/hip_runtime.h>
#include <math.h>

#define Dm 128
#define Ssz 120
#define Bsz 16
#define Tcy 8
#define Hh 4
#define DA 32
#define Lly 2
#define RT 8                    // rows per block tile (120 % 8 == 0)
#define NRT ((Bsz*Ssz)/RT)      // 240 row-tile blocks
#define NROW (Bsz*Ssz)          // 1920 rows

// transposed-weight buffer offsets (floats)
#define WT_QKV 0                // [out][l][hcol][i]  3*2*128*128
#define WT_WO  98304            // [l][j][k]          2*128*128
#define WT_F1  131072           // [l][c][i]          2*512*128
#define WT_F2  262144           // [l][j][k]          2*128*256
#define WT_E1  327680           // [rbk][j][i]        2*128*128
#define WT_E2  360448
#define WT_CW  393216           // [l][o][k][i]       2*128*3*128
#define WT_TOT 491520

struct KParams {
    const float *meas, *event_, *leak, *event_leak, *bias;
    const float *pm_w, *pm_b, *pe_w, *pe_b, *pl_w, *pl_b, *pel_w, *pel_b;
    const float *stab_emb, *cyc_emb;
    const float *er_ln_s, *er_ln_b, *er_fc1_w, *er_fc1_b, *er_fc2_w, *er_fc2_b;
    const float *ln1_s, *ln1_b, *Wb, *Wq, *bq, *Wk, *bk, *Wv, *bv, *Wo, *bo;
    const float *ln2_s, *ln2_b, *f1_w, *f1_b, *f2_w, *f2_b, *conv_w, *conv_b;
    const float *lnf_s, *lnf_b, *Pp, *sc_w, *sc_b, *dr_w, *dr_b;
    const float *rb1_w, *rb1_b, *rb2_w, *rb2_b, *out_w, *out_b;
    const int *stab_ids, *cycle_ids;
    float *Bp, *Q, *K, *V, *Y2, *E, *wT;
};

__device__ __forceinline__ float gelu_f(float x) {
    return 0.5f * x * (1.0f + erff(x * 0.70710678118654752f));
}
__device__ __forceinline__ float dot4(float4 a, float4 b) {
    return a.x * b.x + a.y * b.y + a.z * b.z + a.w * b.w;
}

// XCD-pinning swizzle: grid = 16*per_b blocks, dispatch round-robins XCD = i&7.
__device__ __forceinline__ int swz16(int i, int per_b) {
    return ((((i & 7) << 1) | ((i >> 3) & 1)) * per_b) + (i >> 4);
}

// LayerNorm 8 rows, >=512 threads; wave w handles row w. src may equal dst.
__device__ __forceinline__ void ln_rows8(const float (*src)[Dm], float (*dst)[Dm],
                                         const float* sg, const float* bg, int tid) {
    int r = tid >> 6, g = tid & 63;
    float x0 = src[r][g], x1 = src[r][g + 64];
    float s1 = x0 + x1;
#pragma unroll
    for (int off = 32; off; off >>= 1) s1 += __shfl_xor(s1, off);
    float m = s1 * (1.f / 128.f);
    float d0 = x0 - m, d1 = x1 - m;
    float s2 = d0 * d0 + d1 * d1;
#pragma unroll
    for (int off = 32; off; off >>= 1) s2 += __shfl_xor(s2, off);
    float rstd = rsqrtf(s2 * (1.f / 128.f) + 1e-5f);
    dst[r][g]      = d0 * rstd * sg[g]      + bg[g];
    dst[r][g + 64] = d1 * rstd * sg[g + 64] + bg[g + 64];
}

// LayerNorm 32 rows, 512 threads, 16 lanes/row (8 elems each).
__device__ __forceinline__ void ln32(const float (*src)[Dm], float (*dst)[Dm],
                                     const float* sg, const float* bg, int tid) {
    int r = tid >> 4, g = tid & 15;
    float v[8];
    float s1 = 0.f;
#pragma unroll
    for (int k = 0; k < 8; k++) { v[k] = src[r][g + 16 * k]; s1 += v[k]; }
#pragma unroll
    for (int off = 8; off; off >>= 1) s1 += __shfl_xor(s1, off);
    float m = s1 * (1.f / 128.f);
    float s2 = 0.f;
#pragma unroll
    for (int k = 0; k < 8; k++) { float d = v[k] - m; s2 += d * d; }
#pragma unroll
    for (int off = 8; off; off >>= 1) s2 += __shfl_xor(s2, off);
    float rstd = rsqrtf(s2 * (1.f / 128.f) + 1e-5f);
#pragma unroll
    for (int k = 0; k < 8; k++)
        dst[r][g + 16 * k] = (v[k] - m) * rstd * sg[g + 16 * k] + bg[g + 16 * k];
}

// ---- build all transposed weight copies ----
__global__ __launch_bounds__(256) void k_prepw(KParams p) {
    int idx = blockIdx.x * 256 + threadIdx.x;
    if (idx >= WT_TOT) return;
    float v;
    if (idx < WT_WO) {                       // qkvT [out][l][hcol][i]
        int i = idx & 127; int t = idx >> 7;
        int hcol = t & 127; t >>= 7;
        int l = t & 1; int out = t >> 1;
        int h = hcol >> 5, e = hcol & 31;
        const float* W = (out == 0 ? p.Wq : out == 1 ? p.Wk : p.Wv);
        v = W[(((size_t)(l * Hh + h) * Dm) + i) * DA + e];
    } else if (idx < WT_F1) {                // woT [l][j][k]
        int rel = idx - WT_WO;
        int k = rel & 127; int t = rel >> 7;
        int j = t & 127; int l = t >> 7;
        v = p.Wo[(size_t)l * Dm * Dm + k * Dm + j];
    } else if (idx < WT_F2) {                // f1T [l][c][i]
        int rel = idx - WT_F1;
        int i = rel & 127; int t = rel >> 7;
        int c = t & 511; int l = t >> 9;
        v = p.f1_w[(size_t)l * Dm * 512 + i * 512 + c];
    } else if (idx < WT_E1) {                // f2T [l][j][k]
        int rel = idx - WT_F2;
        int k = rel & 255; int t = rel >> 8;
        int j = t & 127; int l = t >> 7;
        v = p.f2_w[(size_t)l * 256 * Dm + k * Dm + j];
    } else if (idx < WT_E2) {                // er1T [rbk][j][i]
        int rel = idx - WT_E1;
        int i = rel & 127; int t = rel >> 7;
        int j = t & 127; int rbk = t >> 7;
        v = p.er_fc1_w[(size_t)rbk * Dm * Dm + i * Dm + j];
    } else if (idx < WT_CW) {                // er2T [rbk][j][i]
        int rel = idx - WT_E2;
        int i = rel & 127; int t = rel >> 7;
        int j = t & 127; int rbk = t >> 7;
        v = p.er_fc2_w[(size_t)rbk * Dm * Dm + i * Dm + j];
    } else {                                 // cwT2 [l][o][k][i]
        int rel = idx - WT_CW;
        int i = rel & 127; int t = rel >> 7;
        int k = t % 3; t /= 3;
        int o = t & 127; int l = t >> 7;
        v = p.conv_w[(((size_t)l * Dm + o) * Dm + i) * 3 + k];
    }
    p.wT[idx] = v;
}

// ---- Bp[l,b,h,i,j] = sum_c bias[b,i,j,c] * Wb[l,c,h]; both l per block ----
__global__ __launch_bounds__(128) void k_bias(KParams p) {
    int blk = blockIdx.x;                    // b*S + i
    int b = blk / Ssz, i = blk % Ssz;
    int j = threadIdx.x;
    if (j >= Ssz) return;
    const float4* br4 = (const float4*)(p.bias + ((size_t)(b * Ssz + i) * Ssz + j) * 32);
    float a[Lly][4];
#pragma unroll
    for (int l = 0; l < Lly; l++)
#pragma unroll
        for (int h = 0; h < 4; h++) a[l][h] = 0.f;
#pragma unroll
    for (int c4 = 0; c4 < 8; c4++) {
        float bv[4]; *(float4*)bv = br4[c4];
#pragma unroll
        for (int u = 0; u < 4; u++) {
#pragma unroll
            for (int l = 0; l < Lly; l++) {
                const float* w = p.Wb + (l * 32 + c4 * 4 + u) * Hh;
                a[l][0] += bv[u] * w[0]; a[l][1] += bv[u] * w[1];
                a[l][2] += bv[u] * w[2]; a[l][3] += bv[u] * w[3];
            }
        }
    }
    size_t hs = (size_t)Ssz * Ssz;
#pragma unroll
    for (int l = 0; l < Lly; l++) {
        size_t base = (((size_t)(l * Bsz + b) * Hh) * Ssz + i) * Ssz + j;
        p.Bp[base] = a[l][0]; p.Bp[base + hs] = a[l][1];
        p.Bp[base + 2 * hs] = a[l][2]; p.Bp[base + 3 * hs] = a[l][3];
    }
}

// ---- precompute E[t,row,:] for ALL cycles.  grid 8*60=480, 512 thr, 32 rows ----
__global__ __launch_bounds__(512) void k_embed_all(KParams p) {
    __shared__ float h[32][Dm], hn[32][Dm], t1[32][Dm];
    int t = blockIdx.x / 60, tile = blockIdx.x % 60;
    int row0 = tile * 32;
    int tid = threadIdx.x;
    int cid = p.cycle_ids[t];
    for (int idx = tid; idx < 32 * Dm; idx += 512) {
        int r = idx >> 7, j = idx & 127;
        int row = row0 + r;
        int b = row / Ssz, s = row % Ssz;
        int sid = p.stab_ids[s];
        int mi = (b * Tcy + t) * Ssz + s;
        h[r][j] = p.meas[mi] * p.pm_w[j] + p.pm_b[j]
                + p.event_[mi] * p.pe_w[j] + p.pe_b[j]
                + p.leak[mi] * p.pl_w[j] + p.pl_b[j]
                + p.event_leak[mi] * p.pel_w[j] + p.pel_b[j]
                + p.stab_emb[sid * Dm + j] + p.cyc_emb[cid * Dm + j];
    }
    __syncthreads();
    int g2 = tid >> 7, j = tid & 127;     // rows 8*g2 .. 8*g2+7
    for (int rbk = 0; rbk < 2; rbk++) {
        ln32(h, hn, p.er_ln_s + rbk * Dm, p.er_ln_b + rbk * Dm, tid);
        __syncthreads();
        const float* W1c = p.wT + WT_E1 + (((size_t)rbk * Dm + j) << 7);
        float acc[8];
#pragma unroll
        for (int rr = 0; rr < 8; rr++) acc[rr] = 0.f;
#pragma unroll 2
        for (int i4 = 0; i4 < 32; i4++) {
            float4 w4 = *(const float4*)&W1c[i4 * 4];
#pragma unroll
            for (int rr = 0; rr < 8; rr++)
                acc[rr] += dot4(*(const float4*)&hn[8 * g2 + rr][i4 * 4], w4);
        }
        float b1 = p.er_fc1_b[rbk * Dm + j];
#pragma unroll
        for (int rr = 0; rr < 8; rr++) t1[8 * g2 + rr][j] = gelu_f(acc[rr] + b1);
        __syncthreads();
        const float* W2c = p.wT + WT_E2 + (((size_t)rbk * Dm + j) << 7);
#pragma unroll
        for (int rr = 0; rr < 8; rr++) acc[rr] = 0.f;
#pragma unroll 2
        for (int i4 = 0; i4 < 32; i4++) {
            float4 w4 = *(const float4*)&W2c[i4 * 4];
#pragma unroll
            for (int rr = 0; rr < 8; rr++)
                acc[rr] += dot4(*(const float4*)&t1[8 * g2 + rr][i4 * 4], w4);
        }
        float b2 = p.er_fc2_b[rbk * Dm + j];
#pragma unroll
        for (int rr = 0; rr < 8; rr++) h[8 * g2 + rr][j] += acc[rr] + b2;
        __syncthreads();
    }
    for (int idx = tid; idx < 32 * Dm; idx += 512) {
        int r = idx >> 7, jj = idx & 127;
        p.E[((size_t)t * NROW + row0 + r) * Dm + jj] = h[r][jj];
    }
}

// ---- phase A: [conv(prev step) if doConv] + [X=(X+E)/sqrt2 if l==0] + ln1 + QKV ----
__global__ __launch_bounds__(512) void k_a(KParams p, const float* Xprev, float* Xcur,
                                           int l, int t, int doConv) {
    __shared__ float xr[RT + 2][Dm];
    __shared__ float xn[RT][Dm];
    int rb = swz16(blockIdx.x, Ssz / RT);
    int row0 = rb * RT;
    int b = row0 / Ssz, s0 = row0 % Ssz;
    int tid = threadIdx.x;
    const float inv = 0.70710678118654752f;
    int g2 = tid >> 7, j = tid & 127;      // rows 2*g2, 2*g2+1

    if (doConv) {
        int lconv = l ^ 1;
        {
            float4* xr4 = (float4*)&xr[0][0];
            for (int i = tid; i < (RT + 2) * Dm / 4; i += 512) {
                int rr = i >> 5, c = i & 31;
                int s = s0 + rr - 1;
                float4 v = make_float4(0.f, 0.f, 0.f, 0.f);
                if (s >= 0 && s < Ssz) v = *(const float4*)(Xprev + (b * Ssz + s) * Dm + 4 * c);
                xr4[i] = v;
            }
        }
        __syncthreads();
        const float* CW = p.wT + WT_CW + ((((size_t)lconv * Dm + j) * 3) << 7);
        float a0 = 0.f, a1 = 0.f;
#pragma unroll 2
        for (int i4 = 0; i4 < 32; i4++) {
            float4 w0 = *(const float4*)&CW[i4 * 4];
            float4 w1 = *(const float4*)&CW[128 + i4 * 4];
            float4 w2 = *(const float4*)&CW[256 + i4 * 4];
            float4 x0 = *(const float4*)&xr[2 * g2][i4 * 4];
            float4 x1 = *(const float4*)&xr[2 * g2 + 1][i4 * 4];
            float4 x2 = *(const float4*)&xr[2 * g2 + 2][i4 * 4];
            float4 x3 = *(const float4*)&xr[2 * g2 + 3][i4 * 4];
            a0 += dot4(w0, x0) + dot4(w1, x1) + dot4(w2, x2);
            a1 += dot4(w0, x1) + dot4(w1, x2) + dot4(w2, x3);
        }
        float cb = p.conv_b[lconv * Dm + j];
        float v0 = xr[2 * g2 + 1][j] + gelu_f(a0 + cb);
        float v1 = xr[2 * g2 + 2][j] + gelu_f(a1 + cb);
        if (l == 0) {
            v0 = (v0 + p.E[((size_t)t * NROW + row0 + 2 * g2) * Dm + j]) * inv;
            v1 = (v1 + p.E[((size_t)t * NROW + row0 + 2 * g2 + 1) * Dm + j]) * inv;
        }
        Xcur[(row0 + 2 * g2) * Dm + j]     = v0;
        Xcur[(row0 + 2 * g2 + 1) * Dm + j] = v1;
        xn[2 * g2][j] = v0; xn[2 * g2 + 1][j] = v1;
    } else {
        // step 0: X starts at zero; X = (0 + E[0])/sqrt2
        float v0 = p.E[(size_t)(row0 + 2 * g2) * Dm + j] * inv;
        float v1 = p.E[(size_t)(row0 + 2 * g2 + 1) * Dm + j] * inv;
        Xcur[(row0 + 2 * g2) * Dm + j]     = v0;
        Xcur[(row0 + 2 * g2 + 1) * Dm + j] = v1;
        xn[2 * g2][j] = v0; xn[2 * g2 + 1][j] = v1;
    }
    __syncthreads();
    ln_rows8(xn, xn, p.ln1_s + l * Dm, p.ln1_b + l * Dm, tid);
    __syncthreads();
    if (tid < 384) {
        int out = tid >> 7, col = tid & 127;     // out: 0=Q 1=K 2=V; col=hcol
        int h = col >> 5, e = col & 31;
        const float* Wc = p.wT + WT_QKV + (((size_t)(out * Lly + l) * Dm + col) << 7);
        const float* bbp = (out == 0 ? p.bq : out == 1 ? p.bk : p.bv) + (l * Hh + h) * DA + e;
        float acc[8];
#pragma unroll
        for (int rr = 0; rr < 8; rr++) acc[rr] = 0.f;
#pragma unroll 2
        for (int i4 = 0; i4 < 32; i4++) {
            float4 w4 = *(const float4*)&Wc[i4 * 4];
#pragma unroll
            for (int rr = 0; rr < 8; rr++)
                acc[rr] += dot4(*(const float4*)&xn[rr][i4 * 4], w4);
        }
        float bv = bbp[0];
        if (out == 2) {
            float* vb = p.V + ((size_t)(b * Hh + h) * DA + e) * Ssz + s0;
            *(float4*)vb       = make_float4(acc[0] + bv, acc[1] + bv, acc[2] + bv, acc[3] + bv);
            *(float4*)(vb + 4) = make_float4(acc[4] + bv, acc[5] + bv, acc[6] + bv, acc[7] + bv);
        } else {
            float* dst = (out == 0 ? p.Q : p.K);
            size_t base = ((size_t)(b * Hh + h) * Ssz + s0) * DA + e;
#pragma unroll
            for (int rr = 0; rr < 8; rr++) dst[base + rr * DA] = acc[rr] + bv;
        }
    }
}

// LDS overlay types for k_b (attn and ffn phases never overlap in time)
struct AttnBufs {
    float4 Kh4[Ssz][8];      // swizzled: e4 stored at slot e4^(k&7)
    float4 Vt4[DA][32];      // V^T per head, swizzled: k4 at slot k4^(e&7)
    float sc[RT][Ssz];
    float pvp[2][RT][DA];
};
struct FfnBufs {
    float opW[2][RT][Dm];
    float xres[RT][Dm];
    float xn[RT][Dm];
    float yfg[RT][256];
    float yg[RT][256];
};

// ---- phase B: attention + O-proj + ln2 + gated FFN (X in place).  grid 240, 512 thr ----
__global__ __launch_bounds__(512, 6) void k_b(KParams p, float* X, int l) {
    __shared__ union UB { AttnBufs a; FfnBufs f; } u;
    __shared__ float Yt[RT][Dm];
    __shared__ float dn[RT];
    int rb = swz16(blockIdx.x, Ssz / RT);
    int b = rb / (Ssz / RT), qt = rb % (Ssz / RT);
    int q0 = qt * RT;
    int row0 = rb * RT;
    int tid = threadIdx.x;
    const float scale = 0.17677669529663689f;   // 1/sqrt(32)

    for (int h = 0; h < Hh; h++) {
        __syncthreads();
        {
            const float4* K4 = (const float4*)(p.K + ((size_t)(b * Hh + h) * Ssz) * DA);
            const float4* V4 = (const float4*)(p.V + ((size_t)(b * Hh + h) * DA) * Ssz);
            for (int i = tid; i < 960; i += 512) {
                int k = i >> 3, f = i & 7;
                u.a.Kh4[k][f ^ (k & 7)] = K4[i];
                int e = i / 30, s4 = i % 30;
                u.a.Vt4[e][s4 ^ (e & 7)] = V4[i];
            }
        }
        __syncthreads();
        {
            int r = tid >> 6, c0 = tid & 63;
            int c1 = c0 + 64;
            bool v1 = c1 < Ssz;
            int sw = c0 & 7;
            const float* Bpr = p.Bp + (((size_t)(l * Bsz + b) * Hh + h) * Ssz + q0 + r) * Ssz;
            const float4* Q4r = (const float4*)(p.Q + ((size_t)(b * Hh + h) * Ssz + q0 + r) * DA);
            float d0 = 0.f, d1 = 0.f;
#pragma unroll
            for (int e4 = 0; e4 < 8; e4++) {
                float4 qv = Q4r[e4];                 // broadcast
                float4 k0 = u.a.Kh4[c0][e4 ^ sw];
                d0 += dot4(qv, k0);
                if (v1) d1 += dot4(qv, u.a.Kh4[c1][e4 ^ sw]);
            }
            d0 = (d0 + Bpr[c0]) * scale;
            d1 = v1 ? (d1 + Bpr[c1]) * scale : -1e30f;
            float m = fmaxf(d0, d1);
#pragma unroll
            for (int off = 32; off; off >>= 1) m = fmaxf(m, __shfl_xor(m, off));
            float p0 = expf(d0 - m);
            float p1 = v1 ? expf(d1 - m) : 0.f;
            float s = p0 + p1;
#pragma unroll
            for (int off = 32; off; off >>= 1) s += __shfl_xor(s, off);
            u.a.sc[r][c0] = p0;
            if (v1) u.a.sc[r][c1] = p1;
            if (c0 == 0) dn[r] = s;
        }
        __syncthreads();
        {
            int half = tid >> 8, r = (tid >> 5) & 7, m = tid & 31;
            int sw = m & 7;
            int k40 = half * 15;
            float a = 0.f;
#pragma unroll
            for (int k4 = 0; k4 < 15; k4++) {
                float4 s4v = *(const float4*)&u.a.sc[r][(k40 + k4) * 4];   // broadcast
                float4 vv = u.a.Vt4[m][(k40 + k4) ^ sw];
                a += dot4(s4v, vv);
            }
            u.a.pvp[half][r][m] = a;
        }
        __syncthreads();
        if (tid < 256) {
            int r = tid >> 5, m = tid & 31;
            Yt[r][h * DA + m] = (u.a.pvp[0][r][m] + u.a.pvp[1][r][m]) / dn[r];
        }
    }
    __syncthreads();
    {
        int pp = tid >> 8, g2 = (tid >> 7) & 1, j = tid & 127;
        // O-proj split-K (attn buffers dead from here; u.f region live)
        {
            const float* Wc = p.wT + WT_WO + (((size_t)l * Dm + j) << 7);
            float a[4] = {0.f, 0.f, 0.f, 0.f};
            for (int k4 = pp * 16; k4 < pp * 16 + 16; k4++) {
                float4 w4 = *(const float4*)&Wc[k4 * 4];
#pragma unroll
                for (int rr = 0; rr < 4; rr++)
                    a[rr] += dot4(*(const float4*)&Yt[4 * g2 + rr][k4 * 4], w4);
            }
#pragma unroll
            for (int rr = 0; rr < 4; rr++) u.f.opW[pp][4 * g2 + rr][j] = a[rr];
        }
        __syncthreads();
        for (int idx = tid; idx < RT * Dm; idx += 512) {
            int r = idx >> 7, j2 = idx & 127;
            float xv = X[(row0 + r) * Dm + j2] + u.f.opW[0][r][j2] + u.f.opW[1][r][j2] + p.bo[l * Dm + j2];
            u.f.xres[r][j2] = xv;
            u.f.xn[r][j2] = xv;
        }
        __syncthreads();
        ln_rows8(u.f.xn, u.f.xn, p.ln2_s + l * Dm, p.ln2_b + l * Dm, tid);
        __syncthreads();
        // f1: thread owns one of 512 cols; gate via LDS exchange
        {
            const float* Wc = p.wT + WT_F1 + (((size_t)l * 512 + tid) << 7);
            float acc[8];
#pragma unroll
            for (int rr = 0; rr < 8; rr++) acc[rr] = 0.f;
#pragma unroll 2
            for (int i4 = 0; i4 < 32; i4++) {
                float4 w4 = *(const float4*)&Wc[i4 * 4];
#pragma unroll
                for (int rr = 0; rr < 8; rr++)
                    acc[rr] += dot4(*(const float4*)&u.f.xn[rr][i4 * 4], w4);
            }
            if (tid >= 256) {
#pragma unroll
                for (int rr = 0; rr < 8; rr++) u.f.yfg[rr][tid - 256] = acc[rr];
            }
            __syncthreads();
            if (tid < 256) {
                float b1a = p.f1_b[l * 512 + tid];
                float b1g = p.f1_b[l * 512 + 256 + tid];
#pragma unroll
                for (int rr = 0; rr < 8; rr++)
                    u.f.yg[rr][tid] = gelu_f(acc[rr] + b1a) * (u.f.yfg[rr][tid] + b1g);
            }
        }
        __syncthreads();
        // f2 split-K
        {
            const float* Wc = p.wT + WT_F2 + (((size_t)l * Dm + j) << 8);
            float a[4] = {0.f, 0.f, 0.f, 0.f};
            for (int k4 = pp * 32; k4 < pp * 32 + 32; k4++) {
                float4 w4 = *(const float4*)&Wc[k4 * 4];
#pragma unroll
                for (int rr = 0; rr < 4; rr++)
                    a[rr] += dot4(*(const float4*)&u.f.yg[4 * g2 + rr][k4 * 4], w4);
            }
#pragma unroll
            for (int rr = 0; rr < 4; rr++) u.f.opW[pp][4 * g2 + rr][j] = a[rr];
        }
        __syncthreads();
        for (int idx = tid; idx < RT * Dm; idx += 512) {
            int r = idx >> 7, j2 = idx & 127;
            X[(row0 + r) * Dm + j2] = u.f.xres[r][j2] + u.f.opW[0][r][j2] + u.f.opW[1][r][j2] + p.f2_b[l * Dm + j2];
        }
    }
}

// ---- standalone conv (final step only).  grid 240, 256 thr ----
__global__ __launch_bounds__(256) void k_conv(KParams p, const float* Xin, float* Xout, int l) {
    __shared__ float xr[RT + 2][Dm];
    int rb = swz16(blockIdx.x, Ssz / RT);
    int row0 = rb * RT;
    int b = row0 / Ssz, s0 = row0 % Ssz;
    int tid = threadIdx.x;
    {
        float4* xr4 = (float4*)&xr[0][0];
        for (int i = tid; i < (RT + 2) * Dm / 4; i += 256) {
            int rr = i >> 5, c = i & 31;
            int s = s0 + rr - 1;
            float4 v = make_float4(0.f, 0.f, 0.f, 0.f);
            if (s >= 0 && s < Ssz) v = *(const float4*)(Xin + (b * Ssz + s) * Dm + 4 * c);
            xr4[i] = v;
        }
    }
    __syncthreads();
    int g = tid >> 7, j = tid & 127;      // rows 4g..4g+3
    const float* CW = p.wT + WT_CW + ((((size_t)l * Dm + j) * 3) << 7);
    float a[4] = {0.f, 0.f, 0.f, 0.f};
#pragma unroll 2
    for (int i4 = 0; i4 < 32; i4++) {
        float4 w0 = *(const float4*)&CW[i4 * 4];
        float4 w1 = *(const float4*)&CW[128 + i4 * 4];
        float4 w2 = *(const float4*)&CW[256 + i4 * 4];
        float4 xv[6];
#pragma unroll
        for (int rr = 0; rr < 6; rr++) xv[rr] = *(const float4*)&xr[4 * g + rr][i4 * 4];
#pragma unroll
        for (int rr = 0; rr < 4; rr++)
            a[rr] += dot4(w0, xv[rr]) + dot4(w1, xv[rr + 1]) + dot4(w2, xv[rr + 2]);
    }
    float cb = p.conv_b[l * Dm + j];
#pragma unroll
    for (int rr = 0; rr < 4; rr++)
        Xout[(row0 + 4 * g + rr) * Dm + j] = xr[4 * g + rr + 1][j] + gelu_f(a[rr] + cb);
}

// ---- fused readout: lnf (inline) + scale-conv + gelu + dim-reduce.  grid 576, 128 thr ----
__global__ __launch_bounds__(128) void k_head(KParams p, const float* X) {
    int blk = swz16(blockIdx.x, 36);
    int b = blk / 36, r2 = blk % 36, oh = r2 / 6, ow = r2 % 6;
    __shared__ float cells[4][Dm];
    __shared__ float sx[Dm];
    int tid = threadIdx.x;
    {
        int c = tid >> 5, lane = tid & 31;
        int cell = (2 * oh + (c >> 1)) * 12 + (2 * ow + (c & 1));
        if (cell < Ssz) {
            const float* Xr = X + (size_t)(b * Ssz + cell) * Dm;
            float v[4];
            float s1 = 0.f;
#pragma unroll
            for (int k = 0; k < 4; k++) { v[k] = Xr[lane + 32 * k]; s1 += v[k]; }
#pragma unroll
            for (int off = 16; off; off >>= 1) s1 += __shfl_xor(s1, off);
            float m = s1 * (1.f / 128.f);
            float s2 = 0.f;
#pragma unroll
            for (int k = 0; k < 4; k++) { float d = v[k] - m; s2 += d * d; }
#pragma unroll
            for (int off = 16; off; off >>= 1) s2 += __shfl_xor(s2, off);
            float rstd = rsqrtf(s2 * (1.f / 128.f) + 1e-5f);
#pragma unroll
            for (int k = 0; k < 4; k++) {
                int jj = lane + 32 * k;
                cells[c][jj] = (v[k] - m) * rstd * p.lnf_s[jj] + p.lnf_b[jj];
            }
        } else {
#pragma unroll
            for (int k = 0; k < 4; k++) cells[c][lane + 32 * k] = p.Pp[lane + 32 * k];
        }
    }
    __syncthreads();
    int j = tid;
    float acc = p.sc_b[j];
    const float* W = p.sc_w + (size_t)j * Dm * 4;   // [o=j][i][kh][kw]
    for (int i = 0; i < Dm; i++) {
        acc += W[i * 4 + 0] * cells[0][i] + W[i * 4 + 1] * cells[1][i]
             + W[i * 4 + 2] * cells[2][i] + W[i * 4 + 3] * cells[3][i];
    }
    sx[j] = gelu_f(acc);
    __syncthreads();
    if (j < 48) {
        float a = p.dr_b[j];
        const float* w = p.dr_w + j * Dm;
        for (int i = 0; i < Dm; i++) a += sx[i] * w[i];
        p.Y2[((b * 6 + ow) * 6 + oh) * 48 + j] = gelu_f(a);
    }
}

// ---- mean over oh + 16 resblocks + out_w dot + mean over ow.  grid 16, 320 thr ----
__global__ __launch_bounds__(320) void k_rb2(KParams p, float* out) {
    int b = swz16(blockIdx.x, 1);
    __shared__ float x[6][48], t[6][48], red[6];
    int tid = threadIdx.x;
    int ow = tid / 48, j = tid % 48;
    bool act = tid < 288;
    if (act) {
        float s = 0.f;
#pragma unroll
        for (int oh = 0; oh < 6; oh++) s += p.Y2[((b * 6 + ow) * 6 + oh) * 48 + j];
        x[ow][j] = s * (1.f / 6.f);
    }
    __syncthreads();
    for (int r = 0; r < 16; r++) {
        if (act) {
            float a = p.rb1_b[r * 48 + j];
            const float* W = p.rb1_w + (size_t)r * 48 * 48 + j;
            for (int i = 0; i < 48; i++) a += x[ow][i] * W[i * 48];
            t[ow][j] = gelu_f(a);
        }
        __syncthreads();
        if (act) {
            float a = p.rb2_b[r * 48 + j];
            const float* W = p.rb2_w + (size_t)r * 48 * 48 + j;
            for (int i = 0; i < 48; i++) a += t[ow][i] * W[i * 48];
            x[ow][j] += a;
        }
        __syncthreads();
    }
    if (act) t[ow][j] = x[ow][j] * p.out_w[j];
    __syncthreads();
    if (tid < 6) {
        float s = 0.f;
        for (int i = 0; i < 48; i++) s += t[tid][i];
        red[tid] = s;
    }
    __syncthreads();
    if (tid == 0) {
        float s = 0.f;
#pragma unroll
        for (int w = 0; w < 6; w++) s += red[w];
        out[b] = s * (1.f / 6.f) + p.out_b[0];
    }
}

extern "C" void kernel_launch(void* const* d_in, const int* in_sizes, int n_in,
                              void* d_out, int out_size, void* d_ws, size_t ws_size,
                              hipStream_t stream) {
    KParams p;
    p.meas       = (const float*)d_in[0];
    p.event_     = (const float*)d_in[1];
    p.leak       = (const float*)d_in[2];
    p.event_leak = (const float*)d_in[3];
    p.bias       = (const float*)d_in[4];
    p.pm_w  = (const float*)d_in[5];  p.pm_b  = (const float*)d_in[6];
    p.pe_w  = (const float*)d_in[7];  p.pe_b  = (const float*)d_in[8];
    p.pl_w  = (const float*)d_in[9];  p.pl_b  = (const float*)d_in[10];
    p.pel_w = (const float*)d_in[11]; p.pel_b = (const float*)d_in[12];
    p.stab_emb = (const float*)d_in[13];
    p.cyc_emb  = (const float*)d_in[14];
    p.er_ln_s  = (const float*)d_in[15]; p.er_ln_b  = (const float*)d_in[16];
    p.er_fc1_w = (const float*)d_in[17]; p.er_fc1_b = (const float*)d_in[18];
    p.er_fc2_w = (const float*)d_in[19]; p.er_fc2_b = (const float*)d_in[20];
    p.ln1_s = (const float*)d_in[21]; p.ln1_b = (const float*)d_in[22];
    p.Wb = (const float*)d_in[23];
    p.Wq = (const float*)d_in[24]; p.bq = (const float*)d_in[25];
    p.Wk = (const float*)d_in[26]; p.bk = (const float*)d_in[27];
    p.Wv = (const float*)d_in[28]; p.bv = (const float*)d_in[29];
    p.Wo = (const float*)d_in[30]; p.bo = (const float*)d_in[31];
    p.ln2_s = (const float*)d_in[32]; p.ln2_b = (const float*)d_in[33];
    p.f1_w = (const float*)d_in[34]; p.f1_b = (const float*)d_in[35];
    p.f2_w = (const float*)d_in[36]; p.f2_b = (const float*)d_in[37];
    p.conv_w = (const float*)d_in[38]; p.conv_b = (const float*)d_in[39];
    p.lnf_s = (const float*)d_in[40]; p.lnf_b = (const float*)d_in[41];
    p.Pp   = (const float*)d_in[42];
    p.sc_w = (const float*)d_in[43]; p.sc_b = (const float*)d_in[44];
    p.dr_w = (const float*)d_in[45]; p.dr_b = (const float*)d_in[46];
    p.rb1_w = (const float*)d_in[47]; p.rb1_b = (const float*)d_in[48];
    p.rb2_w = (const float*)d_in[49]; p.rb2_b = (const float*)d_in[50];
    p.out_w = (const float*)d_in[51]; p.out_b = (const float*)d_in[52];
    p.stab_ids  = (const int*)d_in[53];
    p.cycle_ids = (const int*)d_in[54];

    float* ws = (float*)d_ws;
    size_t off = 0;
    const size_t BP_SZ  = (size_t)Lly * Bsz * Hh * Ssz * Ssz;   // 1,843,200
    const size_t QKV_SZ = (size_t)Bsz * Hh * Ssz * DA;          //   245,760
    const size_t X_SZ   = (size_t)Bsz * Ssz * Dm;               //   245,760
    const size_t E_SZ   = (size_t)Tcy * NROW * Dm;              // 1,966,080
    p.Bp = ws + off; off += BP_SZ;
    p.Q  = ws + off; off += QKV_SZ;
    p.K  = ws + off; off += QKV_SZ;
    p.V  = ws + off; off += QKV_SZ;      // V stored transposed [b][h][e][s]
    float* X0 = ws + off; off += X_SZ;
    float* X1 = ws + off; off += X_SZ;
    p.Y2  = ws + off; off += (size_t)Bsz * 6 * 6 * 48;
    p.E   = ws + off; off += E_SZ;
    p.wT  = ws + off; off += WT_TOT;

    k_prepw<<<(WT_TOT + 255) / 256, 256, 0, stream>>>(p);
    k_bias<<<Bsz * Ssz, 128, 0, stream>>>(p);
    k_embed_all<<<Tcy * 60, 512, 0, stream>>>(p);

    float* Xbuf[2] = {X0, X1};
    for (int step = 0; step < Tcy * Lly; step++) {
        int t = step >> 1, l = step & 1;
        float* Xcur = Xbuf[step & 1];
        const float* Xprev = (step == 0) ? X0 : Xbuf[(step + 1) & 1];
        k_a<<<NRT, 512, 0, stream>>>(p, Xprev, Xcur, l, t, step > 0 ? 1 : 0);
        k_b<<<NRT, 512, 0, stream>>>(p, Xcur, l);
    }
    // conv of the last step (step 15, l=1): X1 -> X0, then readout from X0
    k_conv<<<NRT, 256, 0, stream>>>(p, X1, X0, 1);
    k_head<<<Bsz * 36, 128, 0, stream>>>(p, X0);
    k_rb2<<<Bsz, 320, 0, stream>>>(p, (float*)d_out);
}

// Round 11
// 1252.832 us; speedup vs baseline: 1.3810x; 1.3810x over previous
//
#include <hip/hip_runtime.h>
#include <math.h>

#define Dm 128
#define Ssz 120
#define Bsz 16
#define Tcy 8
#define Hh 4
#define DA 32
#define Lly 2
#define RT 8                    // rows per block tile (120 % 8 == 0)
#define NRT ((Bsz*Ssz)/RT)      // 240 row-tile blocks
#define NROW (Bsz*Ssz)          // 1920 rows

struct KParams {
    const float *meas, *event_, *leak, *event_leak, *bias;
    const float *pm_w, *pm_b, *pe_w, *pe_b, *pl_w, *pl_b, *pel_w, *pel_b;
    const float *stab_emb, *cyc_emb;
    const float *er_ln_s, *er_ln_b, *er_fc1_w, *er_fc1_b, *er_fc2_w, *er_fc2_b;
    const float *ln1_s, *ln1_b, *Wb, *Wq, *bq, *Wk, *bk, *Wv, *bv, *Wo, *bo;
    const float *ln2_s, *ln2_b, *f1_w, *f1_b, *f2_w, *f2_b, *conv_w, *conv_b;
    const float *lnf_s, *lnf_b, *Pp, *sc_w, *sc_b, *dr_w, *dr_b;
    const float *rb1_w, *rb1_b, *rb2_w, *rb2_b, *out_w, *out_b;
    const int *stab_ids, *cycle_ids;
    float *Bp, *Q, *K, *V, *Y2, *cwT, *E;
};

__device__ __forceinline__ float gelu_f(float x) {
    return 0.5f * x * (1.0f + erff(x * 0.70710678118654752f));
}

// XCD-pinning swizzle: grid = 16*per_b blocks, dispatch round-robins XCD = i&7.
__device__ __forceinline__ int swz16(int i, int per_b) {
    return ((((i & 7) << 1) | ((i >> 3) & 1)) * per_b) + (i >> 4);
}

// LayerNorm 8 rows, >=512 threads; wave w handles row w. src may equal dst.
__device__ __forceinline__ void ln_rows8(const float (*src)[Dm], float (*dst)[Dm],
                                         const float* sg, const float* bg, int tid) {
    int r = tid >> 6, g = tid & 63;
    float x0 = src[r][g], x1 = src[r][g + 64];
    float s1 = x0 + x1;
#pragma unroll
    for (int off = 32; off; off >>= 1) s1 += __shfl_xor(s1, off);
    float m = s1 * (1.f / 128.f);
    float d0 = x0 - m, d1 = x1 - m;
    float s2 = d0 * d0 + d1 * d1;
#pragma unroll
    for (int off = 32; off; off >>= 1) s2 += __shfl_xor(s2, off);
    float rstd = rsqrtf(s2 * (1.f / 128.f) + 1e-5f);
    dst[r][g]      = d0 * rstd * sg[g]      + bg[g];
    dst[r][g + 64] = d1 * rstd * sg[g + 64] + bg[g + 64];
}

// LayerNorm 32 rows, 512 threads, 16 lanes/row (8 elems each).
__device__ __forceinline__ void ln32(const float (*src)[Dm], float (*dst)[Dm],
                                     const float* sg, const float* bg, int tid) {
    int r = tid >> 4, g = tid & 15;
    float v[8];
    float s1 = 0.f;
#pragma unroll
    for (int k = 0; k < 8; k++) { v[k] = src[r][g + 16 * k]; s1 += v[k]; }
#pragma unroll
    for (int off = 8; off; off >>= 1) s1 += __shfl_xor(s1, off);
    float m = s1 * (1.f / 128.f);
    float s2 = 0.f;
#pragma unroll
    for (int k = 0; k < 8; k++) { float d = v[k] - m; s2 += d * d; }
#pragma unroll
    for (int off = 8; off; off >>= 1) s2 += __shfl_xor(s2, off);
    float rstd = rsqrtf(s2 * (1.f / 128.f) + 1e-5f);
#pragma unroll
    for (int k = 0; k < 8; k++)
        dst[r][g + 16 * k] = (v[k] - m) * rstd * sg[g + 16 * k] + bg[g + 16 * k];
}

// ---- transpose conv_w (L,O,I,3) -> cwT (L,I,3,O) ----
__global__ __launch_bounds__(256) void k_prepcw(KParams p) {
    int idx = blockIdx.x * 256 + threadIdx.x;
    if (idx >= Lly * Dm * 3 * Dm) return;
    int o = idx & 127; int rest = idx >> 7;
    int k = rest % 3; rest /= 3;
    int i = rest & 127; int l = rest >> 7;
    p.cwT[idx] = p.conv_w[((l * Dm + o) * Dm + i) * 3 + k];
}

// ---- Bp[l,b,h,i,j] = sum_c bias[b,i,j,c] * Wb[l,c,h]; both l per block ----
__global__ __launch_bounds__(128) void k_bias(KParams p) {
    int blk = blockIdx.x;                    // b*S + i
    int b = blk / Ssz, i = blk % Ssz;
    int j = threadIdx.x;
    if (j >= Ssz) return;
    const float4* br4 = (const float4*)(p.bias + ((size_t)(b * Ssz + i) * Ssz + j) * 32);
    float a[Lly][4];
#pragma unroll
    for (int l = 0; l < Lly; l++)
#pragma unroll
        for (int h = 0; h < 4; h++) a[l][h] = 0.f;
#pragma unroll
    for (int c4 = 0; c4 < 8; c4++) {
        float bv[4]; *(float4*)bv = br4[c4];
#pragma unroll
        for (int u = 0; u < 4; u++) {
#pragma unroll
            for (int l = 0; l < Lly; l++) {
                const float* w = p.Wb + (l * 32 + c4 * 4 + u) * Hh;
                a[l][0] += bv[u] * w[0]; a[l][1] += bv[u] * w[1];
                a[l][2] += bv[u] * w[2]; a[l][3] += bv[u] * w[3];
            }
        }
    }
    size_t hs = (size_t)Ssz * Ssz;
#pragma unroll
    for (int l = 0; l < Lly; l++) {
        size_t base = (((size_t)(l * Bsz + b) * Hh) * Ssz + i) * Ssz + j;
        p.Bp[base] = a[l][0]; p.Bp[base + hs] = a[l][1];
        p.Bp[base + 2 * hs] = a[l][2]; p.Bp[base + 3 * hs] = a[l][3];
    }
}

// ---- precompute E[t,row,:] for ALL cycles.  grid 8*60=480, 512 thr, 32 rows ----
__global__ __launch_bounds__(512) void k_embed_all(KParams p) {
    __shared__ float h[32][Dm], hn[32][Dm], t1[32][Dm];
    int t = blockIdx.x / 60, tile = blockIdx.x % 60;
    int row0 = tile * 32;
    int tid = threadIdx.x;
    int cid = p.cycle_ids[t];
    for (int idx = tid; idx < 32 * Dm; idx += 512) {
        int r = idx >> 7, j = idx & 127;
        int row = row0 + r;
        int b = row / Ssz, s = row % Ssz;
        int sid = p.stab_ids[s];
        int mi = (b * Tcy + t) * Ssz + s;
        h[r][j] = p.meas[mi] * p.pm_w[j] + p.pm_b[j]
                + p.event_[mi] * p.pe_w[j] + p.pe_b[j]
                + p.leak[mi] * p.pl_w[j] + p.pl_b[j]
                + p.event_leak[mi] * p.pel_w[j] + p.pel_b[j]
                + p.stab_emb[sid * Dm + j] + p.cyc_emb[cid * Dm + j];
    }
    __syncthreads();
    int g2 = tid >> 7, j = tid & 127;     // rows 8*g2 .. 8*g2+7
    for (int rbk = 0; rbk < 2; rbk++) {
        ln32(h, hn, p.er_ln_s + rbk * Dm, p.er_ln_b + rbk * Dm, tid);
        __syncthreads();
        const float* W1 = p.er_fc1_w + rbk * Dm * Dm;
        float acc[8];
#pragma unroll
        for (int rr = 0; rr < 8; rr++) acc[rr] = 0.f;
#pragma unroll 2
        for (int i4 = 0; i4 < 32; i4++) {
            float4 xv[8];
#pragma unroll
            for (int rr = 0; rr < 8; rr++) xv[rr] = *(const float4*)&hn[8 * g2 + rr][i4 * 4];
#pragma unroll
            for (int u = 0; u < 4; u++) {
                float w = W1[(i4 * 4 + u) * Dm + j];
#pragma unroll
                for (int rr = 0; rr < 8; rr++) acc[rr] += ((const float*)&xv[rr])[u] * w;
            }
        }
        float b1 = p.er_fc1_b[rbk * Dm + j];
#pragma unroll
        for (int rr = 0; rr < 8; rr++) t1[8 * g2 + rr][j] = gelu_f(acc[rr] + b1);
        __syncthreads();
        const float* W2 = p.er_fc2_w + rbk * Dm * Dm;
#pragma unroll
        for (int rr = 0; rr < 8; rr++) acc[rr] = 0.f;
#pragma unroll 2
        for (int i4 = 0; i4 < 32; i4++) {
            float4 xv[8];
#pragma unroll
            for (int rr = 0; rr < 8; rr++) xv[rr] = *(const float4*)&t1[8 * g2 + rr][i4 * 4];
#pragma unroll
            for (int u = 0; u < 4; u++) {
                float w = W2[(i4 * 4 + u) * Dm + j];
#pragma unroll
                for (int rr = 0; rr < 8; rr++) acc[rr] += ((const float*)&xv[rr])[u] * w;
            }
        }
        float b2 = p.er_fc2_b[rbk * Dm + j];
#pragma unroll
        for (int rr = 0; rr < 8; rr++) h[8 * g2 + rr][j] += acc[rr] + b2;
        __syncthreads();
    }
    for (int idx = tid; idx < 32 * Dm; idx += 512) {
        int r = idx >> 7, jj = idx & 127;
        p.E[((size_t)t * NROW + row0 + r) * Dm + jj] = h[r][jj];
    }
}

// ---- phase A: [conv(prev step) if doConv] + [X=(X+E)/sqrt2 if l==0] + ln1 + QKV
//      grid 240, 512 thr.  Q,K layout [b][h][s][e]; V TRANSPOSED [b][h][e][s] ----
__global__ __launch_bounds__(512) void k_a(KParams p, const float* Xprev, float* Xcur,
                                           int l, int t, int doConv) {
    __shared__ float xr[RT + 2][Dm];
    __shared__ float xn[RT][Dm];
    int rb = swz16(blockIdx.x, Ssz / RT);
    int row0 = rb * RT;
    int b = row0 / Ssz, s0 = row0 % Ssz;
    int tid = threadIdx.x;
    const float inv = 0.70710678118654752f;
    int g2 = tid >> 7, j = tid & 127;      // rows 2*g2, 2*g2+1

    if (doConv) {
        int lconv = l ^ 1;
        {
            float4* xr4 = (float4*)&xr[0][0];
            for (int i = tid; i < (RT + 2) * Dm / 4; i += 512) {
                int rr = i >> 5, c = i & 31;
                int s = s0 + rr - 1;
                float4 v = make_float4(0.f, 0.f, 0.f, 0.f);
                if (s >= 0 && s < Ssz) v = *(const float4*)(Xprev + (b * Ssz + s) * Dm + 4 * c);
                xr4[i] = v;
            }
        }
        __syncthreads();
        const float* CW = p.cwT + (size_t)lconv * Dm * 3 * Dm + j;
        float a0 = 0.f, a1 = 0.f;
#pragma unroll 2
        for (int i4 = 0; i4 < 32; i4++) {
            float4 xv[4];
#pragma unroll
            for (int rr = 0; rr < 4; rr++) xv[rr] = *(const float4*)&xr[2 * g2 + rr][i4 * 4];
#pragma unroll
            for (int u = 0; u < 4; u++) {
                int i = i4 * 4 + u;
                float w0 = CW[(i * 3 + 0) * Dm];
                float w1 = CW[(i * 3 + 1) * Dm];
                float w2 = CW[(i * 3 + 2) * Dm];
                a0 += w0 * ((const float*)&xv[0])[u] + w1 * ((const float*)&xv[1])[u] + w2 * ((const float*)&xv[2])[u];
                a1 += w0 * ((const float*)&xv[1])[u] + w1 * ((const float*)&xv[2])[u] + w2 * ((const float*)&xv[3])[u];
            }
        }
        float cb = p.conv_b[lconv * Dm + j];
        float v0 = xr[2 * g2 + 1][j] + gelu_f(a0 + cb);
        float v1 = xr[2 * g2 + 2][j] + gelu_f(a1 + cb);
        if (l == 0) {
            v0 = (v0 + p.E[((size_t)t * NROW + row0 + 2 * g2) * Dm + j]) * inv;
            v1 = (v1 + p.E[((size_t)t * NROW + row0 + 2 * g2 + 1) * Dm + j]) * inv;
        }
        Xcur[(row0 + 2 * g2) * Dm + j]     = v0;
        Xcur[(row0 + 2 * g2 + 1) * Dm + j] = v1;
        xn[2 * g2][j] = v0; xn[2 * g2 + 1][j] = v1;
    } else {
        // step 0: X starts at zero; X = (0 + E[0])/sqrt2
        float v0 = p.E[(size_t)(row0 + 2 * g2) * Dm + j] * inv;
        float v1 = p.E[(size_t)(row0 + 2 * g2 + 1) * Dm + j] * inv;
        Xcur[(row0 + 2 * g2) * Dm + j]     = v0;
        Xcur[(row0 + 2 * g2 + 1) * Dm + j] = v1;
        xn[2 * g2][j] = v0; xn[2 * g2 + 1][j] = v1;
    }
    __syncthreads();
    ln_rows8(xn, xn, p.ln1_s + l * Dm, p.ln1_b + l * Dm, tid);
    __syncthreads();
    if (tid < 384) {
        int out = tid >> 7, col = tid & 127;     // out: 0=Q 1=K 2=V
        int h = col >> 5, e = col & 31;
        const float* W = (out == 0 ? p.Wq : out == 1 ? p.Wk : p.Wv)
                       + ((size_t)(l * Hh + h) * Dm) * DA + e;
        const float* bbp = (out == 0 ? p.bq : out == 1 ? p.bk : p.bv) + (l * Hh + h) * DA + e;
        float acc[8];
#pragma unroll
        for (int rr = 0; rr < 8; rr++) acc[rr] = 0.f;
#pragma unroll 2
        for (int i4 = 0; i4 < 32; i4++) {
            float4 xv[8];
#pragma unroll
            for (int rr = 0; rr < 8; rr++) xv[rr] = *(const float4*)&xn[rr][i4 * 4];
#pragma unroll
            for (int u = 0; u < 4; u++) {
                float w = W[(i4 * 4 + u) * DA];
#pragma unroll
                for (int rr = 0; rr < 8; rr++) acc[rr] += ((const float*)&xv[rr])[u] * w;
            }
        }
        float bv = bbp[0];
        if (out == 2) {
            float* vb = p.V + ((size_t)(b * Hh + h) * DA + e) * Ssz + s0;
            *(float4*)vb       = make_float4(acc[0] + bv, acc[1] + bv, acc[2] + bv, acc[3] + bv);
            *(float4*)(vb + 4) = make_float4(acc[4] + bv, acc[5] + bv, acc[6] + bv, acc[7] + bv);
        } else {
            float* dst = (out == 0 ? p.Q : p.K);
            size_t base = ((size_t)(b * Hh + h) * Ssz + s0) * DA + e;
#pragma unroll
            for (int rr = 0; rr < 8; rr++) dst[base + rr * DA] = acc[rr] + bv;
        }
    }
}

// LDS overlay types for k_b (attn and ffn phases never overlap in time)
struct AttnBufs {
    float4 Kh4[Ssz][8];      // swizzled: e4 stored at slot e4^(k&7)
    float4 Vt4[DA][32];      // V^T per head, swizzled: k4 at slot k4^(e&7)
    float sc[RT][Ssz];
    float pvp[2][RT][DA];
};
struct FfnBufs {
    float opW[2][RT][Dm];
    float xres[RT][Dm];
    float xn[RT][Dm];
    float yfg[RT][256];
    float yg[RT][256];
};

// ---- phase B: attention + O-proj + ln2 + gated FFN (X in place).  grid 240, 512 thr ----
__global__ __launch_bounds__(512, 6) void k_b(KParams p, float* X, int l) {
    __shared__ union UB { AttnBufs a; FfnBufs f; } u;
    __shared__ float Yt[RT][Dm];
    __shared__ float dn[RT];
    int rb = swz16(blockIdx.x, Ssz / RT);
    int b = rb / (Ssz / RT), qt = rb % (Ssz / RT);
    int q0 = qt * RT;
    int row0 = rb * RT;
    int tid = threadIdx.x;
    const float scale = 0.17677669529663689f;   // 1/sqrt(32)

    for (int h = 0; h < Hh; h++) {
        __syncthreads();
        {
            const float4* K4 = (const float4*)(p.K + ((size_t)(b * Hh + h) * Ssz) * DA);
            const float4* V4 = (const float4*)(p.V + ((size_t)(b * Hh + h) * DA) * Ssz);
            for (int i = tid; i < 960; i += 512) {
                int k = i >> 3, f = i & 7;
                u.a.Kh4[k][f ^ (k & 7)] = K4[i];
                int e = i / 30, s4 = i % 30;
                u.a.Vt4[e][s4 ^ (e & 7)] = V4[i];
            }
        }
        __syncthreads();
        {
            int r = tid >> 6, c0 = tid & 63;
            int c1 = c0 + 64;
            bool v1 = c1 < Ssz;
            int sw = c0 & 7;
            const float* Bpr = p.Bp + (((size_t)(l * Bsz + b) * Hh + h) * Ssz + q0 + r) * Ssz;
            const float4* Q4r = (const float4*)(p.Q + ((size_t)(b * Hh + h) * Ssz + q0 + r) * DA);
            float d0 = 0.f, d1 = 0.f;
#pragma unroll
            for (int e4 = 0; e4 < 8; e4++) {
                float4 qv = Q4r[e4];                 // broadcast
                float4 k0 = u.a.Kh4[c0][e4 ^ sw];
                d0 += qv.x * k0.x + qv.y * k0.y + qv.z * k0.z + qv.w * k0.w;
                if (v1) {
                    float4 k1 = u.a.Kh4[c1][e4 ^ sw];
                    d1 += qv.x * k1.x + qv.y * k1.y + qv.z * k1.z + qv.w * k1.w;
                }
            }
            d0 = (d0 + Bpr[c0]) * scale;
            d1 = v1 ? (d1 + Bpr[c1]) * scale : -1e30f;
            float m = fmaxf(d0, d1);
#pragma unroll
            for (int off = 32; off; off >>= 1) m = fmaxf(m, __shfl_xor(m, off));
            float p0 = expf(d0 - m);
            float p1 = v1 ? expf(d1 - m) : 0.f;
            float s = p0 + p1;
#pragma unroll
            for (int off = 32; off; off >>= 1) s += __shfl_xor(s, off);
            u.a.sc[r][c0] = p0;
            if (v1) u.a.sc[r][c1] = p1;
            if (c0 == 0) dn[r] = s;
        }
        __syncthreads();
        {
            int half = tid >> 8, r = (tid >> 5) & 7, m = tid & 31;
            int sw = m & 7;
            int k40 = half * 15;
            float a = 0.f;
#pragma unroll
            for (int k4 = 0; k4 < 15; k4++) {
                float s4v[4];
                *(float4*)s4v = *(const float4*)&u.a.sc[r][(k40 + k4) * 4];   // broadcast
                float4 vv = u.a.Vt4[m][(k40 + k4) ^ sw];
                a += s4v[0] * vv.x + s4v[1] * vv.y + s4v[2] * vv.z + s4v[3] * vv.w;
            }
            u.a.pvp[half][r][m] = a;
        }
        __syncthreads();
        if (tid < 256) {
            int r = tid >> 5, m = tid & 31;
            Yt[r][h * DA + m] = (u.a.pvp[0][r][m] + u.a.pvp[1][r][m]) / dn[r];
        }
    }
    __syncthreads();
    {
        int pp = tid >> 8, g2 = (tid >> 7) & 1, j = tid & 127;
        // O-proj split-K (attn buffers dead from here; u.f region live)
        {
            const float* W = p.Wo + l * Dm * Dm + j;
            float a[4] = {0.f, 0.f, 0.f, 0.f};
            for (int k4 = pp * 16; k4 < pp * 16 + 16; k4++) {
                float4 yv[4];
#pragma unroll
                for (int rr = 0; rr < 4; rr++) yv[rr] = *(const float4*)&Yt[4 * g2 + rr][k4 * 4];
#pragma unroll
                for (int u2 = 0; u2 < 4; u2++) {
                    float w = W[(k4 * 4 + u2) * Dm];
#pragma unroll
                    for (int rr = 0; rr < 4; rr++) a[rr] += ((const float*)&yv[rr])[u2] * w;
                }
            }
#pragma unroll
            for (int rr = 0; rr < 4; rr++) u.f.opW[pp][4 * g2 + rr][j] = a[rr];
        }
        __syncthreads();
        for (int idx = tid; idx < RT * Dm; idx += 512) {
            int r = idx >> 7, j2 = idx & 127;
            float xv = X[(row0 + r) * Dm + j2] + u.f.opW[0][r][j2] + u.f.opW[1][r][j2] + p.bo[l * Dm + j2];
            u.f.xres[r][j2] = xv;
            u.f.xn[r][j2] = xv;
        }
        __syncthreads();
        ln_rows8(u.f.xn, u.f.xn, p.ln2_s + l * Dm, p.ln2_b + l * Dm, tid);
        __syncthreads();
        // f1: thread owns one of 512 cols; gate via LDS exchange
        {
            const float* W1 = p.f1_w + (size_t)l * Dm * 512 + tid;
            float acc[8];
#pragma unroll
            for (int rr = 0; rr < 8; rr++) acc[rr] = 0.f;
#pragma unroll 2
            for (int i4 = 0; i4 < 32; i4++) {
                float4 xv[8];
#pragma unroll
                for (int rr = 0; rr < 8; rr++) xv[rr] = *(const float4*)&u.f.xn[rr][i4 * 4];
#pragma unroll
                for (int u2 = 0; u2 < 4; u2++) {
                    float w = W1[(i4 * 4 + u2) * 512];
#pragma unroll
                    for (int rr = 0; rr < 8; rr++) acc[rr] += ((const float*)&xv[rr])[u2] * w;
                }
            }
            if (tid >= 256) {
#pragma unroll
                for (int rr = 0; rr < 8; rr++) u.f.yfg[rr][tid - 256] = acc[rr];
            }
            __syncthreads();
            if (tid < 256) {
                float b1a = p.f1_b[l * 512 + tid];
                float b1g = p.f1_b[l * 512 + 256 + tid];
#pragma unroll
                for (int rr = 0; rr < 8; rr++)
                    u.f.yg[rr][tid] = gelu_f(acc[rr] + b1a) * (u.f.yfg[rr][tid] + b1g);
            }
        }
        __syncthreads();
        // f2 split-K
        {
            const float* W2 = p.f2_w + (size_t)l * 256 * Dm + j;
            float a[4] = {0.f, 0.f, 0.f, 0.f};
            for (int k4 = pp * 32; k4 < pp * 32 + 32; k4++) {
                float4 yv[4];
#pragma unroll
                for (int rr = 0; rr < 4; rr++) yv[rr] = *(const float4*)&u.f.yg[4 * g2 + rr][k4 * 4];
#pragma unroll
                for (int u2 = 0; u2 < 4; u2++) {
                    float w = W2[(k4 * 4 + u2) * Dm];
#pragma unroll
                    for (int rr = 0; rr < 4; rr++) a[rr] += ((const float*)&yv[rr])[u2] * w;
                }
            }
#pragma unroll
            for (int rr = 0; rr < 4; rr++) u.f.opW[pp][4 * g2 + rr][j] = a[rr];
        }
        __syncthreads();
        for (int idx = tid; idx < RT * Dm; idx += 512) {
            int r = idx >> 7, j2 = idx & 127;
            X[(row0 + r) * Dm + j2] = u.f.xres[r][j2] + u.f.opW[0][r][j2] + u.f.opW[1][r][j2] + p.f2_b[l * Dm + j2];
        }
    }
}

// ---- standalone conv (final step only).  grid 240, 256 thr ----
__global__ __launch_bounds__(256) void k_conv(KParams p, const float* Xin, float* Xout, int l) {
    __shared__ float xr[RT + 2][Dm];
    int rb = swz16(blockIdx.x, Ssz / RT);
    int row0 = rb * RT;
    int b = row0 / Ssz, s0 = row0 % Ssz;
    int tid = threadIdx.x;
    {
        float4* xr4 = (float4*)&xr[0][0];
        for (int i = tid; i < (RT + 2) * Dm / 4; i += 256) {
            int rr = i >> 5, c = i & 31;
            int s = s0 + rr - 1;
            float4 v = make_float4(0.f, 0.f, 0.f, 0.f);
            if (s >= 0 && s < Ssz) v = *(const float4*)(Xin + (b * Ssz + s) * Dm + 4 * c);
            xr4[i] = v;
        }
    }
    __syncthreads();
    int g = tid >> 7, j = tid & 127;      // rows 4g..4g+3
    const float* CW = p.cwT + (size_t)l * Dm * 3 * Dm + j;
    float a[4] = {0.f, 0.f, 0.f, 0.f};
#pragma unroll 2
    for (int i4 = 0; i4 < 32; i4++) {
        float4 xv[6];
#pragma unroll
        for (int rr = 0; rr < 6; rr++) xv[rr] = *(const float4*)&xr[4 * g + rr][i4 * 4];
#pragma unroll
        for (int u = 0; u < 4; u++) {
            int i = i4 * 4 + u;
            float w0 = CW[(i * 3 + 0) * Dm];
            float w1 = CW[(i * 3 + 1) * Dm];
            float w2 = CW[(i * 3 + 2) * Dm];
#pragma unroll
            for (int rr = 0; rr < 4; rr++)
                a[rr] += w0 * ((const float*)&xv[rr])[u]
                       + w1 * ((const float*)&xv[rr + 1])[u]
                       + w2 * ((const float*)&xv[rr + 2])[u];
        }
    }
    float cb = p.conv_b[l * Dm + j];
#pragma unroll
    for (int rr = 0; rr < 4; rr++)
        Xout[(row0 + 4 * g + rr) * Dm + j] = xr[4 * g + rr + 1][j] + gelu_f(a[rr] + cb);
}

// ---- fused readout: lnf (inline) + scale-conv + gelu + dim-reduce.  grid 576, 128 thr ----
__global__ __launch_bounds__(128) void k_head(KParams p, const float* X) {
    int blk = swz16(blockIdx.x, 36);
    int b = blk / 36, r2 = blk % 36, oh = r2 / 6, ow = r2 % 6;
    __shared__ float cells[4][Dm];
    __shared__ float sx[Dm];
    int tid = threadIdx.x;
    {
        int c = tid >> 5, lane = tid & 31;
        int cell = (2 * oh + (c >> 1)) * 12 + (2 * ow + (c & 1));
        if (cell < Ssz) {
            const float* Xr = X + (size_t)(b * Ssz + cell) * Dm;
            float v[4];
            float s1 = 0.f;
#pragma unroll
            for (int k = 0; k < 4; k++) { v[k] = Xr[lane + 32 * k]; s1 += v[k]; }
#pragma unroll
            for (int off = 16; off; off >>= 1) s1 += __shfl_xor(s1, off);
            float m = s1 * (1.f / 128.f);
            float s2 = 0.f;
#pragma unroll
            for (int k = 0; k < 4; k++) { float d = v[k] - m; s2 += d * d; }
#pragma unroll
            for (int off = 16; off; off >>= 1) s2 += __shfl_xor(s2, off);
            float rstd = rsqrtf(s2 * (1.f / 128.f) + 1e-5f);
#pragma unroll
            for (int k = 0; k < 4; k++) {
                int jj = lane + 32 * k;
                cells[c][jj] = (v[k] - m) * rstd * p.lnf_s[jj] + p.lnf_b[jj];
            }
        } else {
#pragma unroll
            for (int k = 0; k < 4; k++) cells[c][lane + 32 * k] = p.Pp[lane + 32 * k];
        }
    }
    __syncthreads();
    int j = tid;
    float acc = p.sc_b[j];
    const float* W = p.sc_w + (size_t)j * Dm * 4;   // [o=j][i][kh][kw]
    for (int i = 0; i < Dm; i++) {
        acc += W[i * 4 + 0] * cells[0][i] + W[i * 4 + 1] * cells[1][i]
             + W[i * 4 + 2] * cells[2][i] + W[i * 4 + 3] * cells[3][i];
    }
    sx[j] = gelu_f(acc);
    __syncthreads();
    if (j < 48) {
        float a = p.dr_b[j];
        const float* w = p.dr_w + j * Dm;
        for (int i = 0; i < Dm; i++) a += sx[i] * w[i];
        p.Y2[((b * 6 + ow) * 6 + oh) * 48 + j] = gelu_f(a);
    }
}

// ---- mean over oh + 16 resblocks + out_w dot + mean over ow.  grid 16, 320 thr ----
__global__ __launch_bounds__(320) void k_rb2(KParams p, float* out) {
    int b = swz16(blockIdx.x, 1);
    __shared__ float x[6][48], t[6][48], red[6];
    int tid = threadIdx.x;
    int ow = tid / 48, j = tid % 48;
    bool act = tid < 288;
    if (act) {
        float s = 0.f;
#pragma unroll
        for (int oh = 0; oh < 6; oh++) s += p.Y2[((b * 6 + ow) * 6 + oh) * 48 + j];
        x[ow][j] = s * (1.f / 6.f);
    }
    __syncthreads();
    for (int r = 0; r < 16; r++) {
        if (act) {
            float a = p.rb1_b[r * 48 + j];
            const float* W = p.rb1_w + (size_t)r * 48 * 48 + j;
            for (int i = 0; i < 48; i++) a += x[ow][i] * W[i * 48];
            t[ow][j] = gelu_f(a);
        }
        __syncthreads();
        if (act) {
            float a = p.rb2_b[r * 48 + j];
            const float* W = p.rb2_w + (size_t)r * 48 * 48 + j;
            for (int i = 0; i < 48; i++) a += t[ow][i] * W[i * 48];
            x[ow][j] += a;
        }
        __syncthreads();
    }
    if (act) t[ow][j] = x[ow][j] * p.out_w[j];
    __syncthreads();
    if (tid < 6) {
        float s = 0.f;
        for (int i = 0; i < 48; i++) s += t[tid][i];
        red[tid] = s;
    }
    __syncthreads();
    if (tid == 0) {
        float s = 0.f;
#pragma unroll
        for (int w = 0; w < 6; w++) s += red[w];
        out[b] = s * (1.f / 6.f) + p.out_b[0];
    }
}

extern "C" void kernel_launch(void* const* d_in, const int* in_sizes, int n_in,
                              void* d_out, int out_size, void* d_ws, size_t ws_size,
                              hipStream_t stream) {
    KParams p;
    p.meas       = (const float*)d_in[0];
    p.event_     = (const float*)d_in[1];
    p.leak       = (const float*)d_in[2];
    p.event_leak = (const float*)d_in[3];
    p.bias       = (const float*)d_in[4];
    p.pm_w  = (const float*)d_in[5];  p.pm_b  = (const float*)d_in[6];
    p.pe_w  = (const float*)d_in[7];  p.pe_b  = (const float*)d_in[8];
    p.pl_w  = (const float*)d_in[9];  p.pl_b  = (const float*)d_in[10];
    p.pel_w = (const float*)d_in[11]; p.pel_b = (const float*)d_in[12];
    p.stab_emb = (const float*)d_in[13];
    p.cyc_emb  = (const float*)d_in[14];
    p.er_ln_s  = (const float*)d_in[15]; p.er_ln_b  = (const float*)d_in[16];
    p.er_fc1_w = (const float*)d_in[17]; p.er_fc1_b = (const float*)d_in[18];
    p.er_fc2_w = (const float*)d_in[19]; p.er_fc2_b = (const float*)d_in[20];
    p.ln1_s = (const float*)d_in[21]; p.ln1_b = (const float*)d_in[22];
    p.Wb = (const float*)d_in[23];
    p.Wq = (const float*)d_in[24]; p.bq = (const float*)d_in[25];
    p.Wk = (const float*)d_in[26]; p.bk = (const float*)d_in[27];
    p.Wv = (const float*)d_in[28]; p.bv = (const float*)d_in[29];
    p.Wo = (const float*)d_in[30]; p.bo = (const float*)d_in[31];
    p.ln2_s = (const float*)d_in[32]; p.ln2_b = (const float*)d_in[33];
    p.f1_w = (const float*)d_in[34]; p.f1_b = (const float*)d_in[35];
    p.f2_w = (const float*)d_in[36]; p.f2_b = (const float*)d_in[37];
    p.conv_w = (const float*)d_in[38]; p.conv_b = (const float*)d_in[39];
    p.lnf_s = (const float*)d_in[40]; p.lnf_b = (const float*)d_in[41];
    p.Pp   = (const float*)d_in[42];
    p.sc_w = (const float*)d_in[43]; p.sc_b = (const float*)d_in[44];
    p.dr_w = (const float*)d_in[45]; p.dr_b = (const float*)d_in[46];
    p.rb1_w = (const float*)d_in[47]; p.rb1_b = (const float*)d_in[48];
    p.rb2_w = (const float*)d_in[49]; p.rb2_b = (const float*)d_in[50];
    p.out_w = (const float*)d_in[51]; p.out_b = (const float*)d_in[52];
    p.stab_ids  = (const int*)d_in[53];
    p.cycle_ids = (const int*)d_in[54];

    float* ws = (float*)d_ws;
    size_t off = 0;
    const size_t BP_SZ  = (size_t)Lly * Bsz * Hh * Ssz * Ssz;   // 1,843,200
    const size_t QKV_SZ = (size_t)Bsz * Hh * Ssz * DA;          //   245,760
    const size_t X_SZ   = (size_t)Bsz * Ssz * Dm;               //   245,760
    const size_t E_SZ   = (size_t)Tcy * NROW * Dm;              // 1,966,080
    p.Bp = ws + off; off += BP_SZ;
    p.Q  = ws + off; off += QKV_SZ;
    p.K  = ws + off; off += QKV_SZ;
    p.V  = ws + off; off += QKV_SZ;      // V stored transposed [b][h][e][s]
    float* X0 = ws + off; off += X_SZ;
    float* X1 = ws + off; off += X_SZ;
    p.Y2  = ws + off; off += (size_t)Bsz * 6 * 6 * 48;
    p.cwT = ws + off; off += (size_t)Lly * Dm * 3 * Dm;
    p.E   = ws + off; off += E_SZ;

    k_prepcw<<<(Lly * Dm * 3 * Dm + 255) / 256, 256, 0, stream>>>(p);
    k_bias<<<Bsz * Ssz, 128, 0, stream>>>(p);
    k_embed_all<<<Tcy * 60, 512, 0, stream>>>(p);

    float* Xbuf[2] = {X0, X1};
    for (int step = 0; step < Tcy * Lly; step++) {
        int t = step >> 1, l = step & 1;
        float* Xcur = Xbuf[step & 1];
        const float* Xprev = (step == 0) ? X0 : Xbuf[(step + 1) & 1];
        k_a<<<NRT, 512, 0, stream>>>(p, Xprev, Xcur, l, t, step > 0 ? 1 : 0);
        k_b<<<NRT, 512, 0, stream>>>(p, Xcur, l);
    }
    // conv of the last step (step 15, l=1): X1 -> X0, then readout from X0
    k_conv<<<NRT, 256, 0, stream>>>(p, X1, X0, 1);
    k_head<<<Bsz * 36, 128, 0, stream>>>(p, X0);
    k_rb2<<<Bsz, 320, 0, stream>>>(p, (float*)d_out);
}

// Round 12
// 823.797 us; speedup vs baseline: 2.1003x; 1.5208x over previous
//
#include <hip/hip_runtime.h>
#include <math.h>

#define Dm 128
#define Ssz 120
#define Bsz 16
#define Tcy 8
#define Hh 4
#define DA 32
#define Lly 2
#define RT 8                    // rows per block tile (120 % 8 == 0)
#define NRT ((Bsz*Ssz)/RT)      // 240 row-tile blocks
#define NROW (Bsz*Ssz)          // 1920 rows

struct KParams {
    const float *meas, *event_, *leak, *event_leak, *bias;
    const float *pm_w, *pm_b, *pe_w, *pe_b, *pl_w, *pl_b, *pel_w, *pel_b;
    const float *stab_emb, *cyc_emb;
    const float *er_ln_s, *er_ln_b, *er_fc1_w, *er_fc1_b, *er_fc2_w, *er_fc2_b;
    const float *ln1_s, *ln1_b, *Wb, *Wq, *bq, *Wk, *bk, *Wv, *bv, *Wo, *bo;
    const float *ln2_s, *ln2_b, *f1_w, *f1_b, *f2_w, *f2_b, *conv_w, *conv_b;
    const float *lnf_s, *lnf_b, *Pp, *sc_w, *sc_b, *dr_w, *dr_b;
    const float *rb1_w, *rb1_b, *rb2_w, *rb2_b, *out_w, *out_b;
    const int *stab_ids, *cycle_ids;
    float *Bp, *Q, *K, *V, *Y2, *cwT, *E;
};

__device__ __forceinline__ float gelu_f(float x) {
    return 0.5f * x * (1.0f + erff(x * 0.70710678118654752f));
}

// XCD-pinning swizzle: grid = 16*per_b blocks, dispatch round-robins XCD = i&7.
__device__ __forceinline__ int swz16(int i, int per_b) {
    return ((((i & 7) << 1) | ((i >> 3) & 1)) * per_b) + (i >> 4);
}

// LayerNorm 8 rows, >=512 threads; wave w handles row w. src may equal dst.
__device__ __forceinline__ void ln_rows8(const float (*src)[Dm], float (*dst)[Dm],
                                         const float* sg, const float* bg, int tid) {
    int r = tid >> 6, g = tid & 63;
    float x0 = src[r][g], x1 = src[r][g + 64];
    float s1 = x0 + x1;
#pragma unroll
    for (int off = 32; off; off >>= 1) s1 += __shfl_xor(s1, off);
    float m = s1 * (1.f / 128.f);
    float d0 = x0 - m, d1 = x1 - m;
    float s2 = d0 * d0 + d1 * d1;
#pragma unroll
    for (int off = 32; off; off >>= 1) s2 += __shfl_xor(s2, off);
    float rstd = rsqrtf(s2 * (1.f / 128.f) + 1e-5f);
    dst[r][g]      = d0 * rstd * sg[g]      + bg[g];
    dst[r][g + 64] = d1 * rstd * sg[g + 64] + bg[g + 64];
}

// LayerNorm 32 rows, 512 threads, 16 lanes/row (8 elems each).
__device__ __forceinline__ void ln32(const float (*src)[Dm], float (*dst)[Dm],
                                     const float* sg, const float* bg, int tid) {
    int r = tid >> 4, g = tid & 15;
    float v[8];
    float s1 = 0.f;
#pragma unroll
    for (int k = 0; k < 8; k++) { v[k] = src[r][g + 16 * k]; s1 += v[k]; }
#pragma unroll
    for (int off = 8; off; off >>= 1) s1 += __shfl_xor(s1, off);
    float m = s1 * (1.f / 128.f);
    float s2 = 0.f;
#pragma unroll
    for (int k = 0; k < 8; k++) { float d = v[k] - m; s2 += d * d; }
#pragma unroll
    for (int off = 8; off; off >>= 1) s2 += __shfl_xor(s2, off);
    float rstd = rsqrtf(s2 * (1.f / 128.f) + 1e-5f);
#pragma unroll
    for (int k = 0; k < 8; k++)
        dst[r][g + 16 * k] = (v[k] - m) * rstd * sg[g + 16 * k] + bg[g + 16 * k];
}

// ---- transpose conv_w (L,O,I,3) -> cwT (L,I,3,O) ----
__global__ __launch_bounds__(256) void k_prepcw(KParams p) {
    int idx = blockIdx.x * 256 + threadIdx.x;
    if (idx >= Lly * Dm * 3 * Dm) return;
    int o = idx & 127; int rest = idx >> 7;
    int k = rest % 3; rest /= 3;
    int i = rest & 127; int l = rest >> 7;
    p.cwT[idx] = p.conv_w[((l * Dm + o) * Dm + i) * 3 + k];
}

// ---- Bp[l,b,h,i,j] = sum_c bias[b,i,j,c] * Wb[l,c,h]; both l per block ----
__global__ __launch_bounds__(128) void k_bias(KParams p) {
    int blk = blockIdx.x;                    // b*S + i
    int b = blk / Ssz, i = blk % Ssz;
    int j = threadIdx.x;
    if (j >= Ssz) return;
    const float4* br4 = (const float4*)(p.bias + ((size_t)(b * Ssz + i) * Ssz + j) * 32);
    float a[Lly][4];
#pragma unroll
    for (int l = 0; l < Lly; l++)
#pragma unroll
        for (int h = 0; h < 4; h++) a[l][h] = 0.f;
#pragma unroll
    for (int c4 = 0; c4 < 8; c4++) {
        float bv[4]; *(float4*)bv = br4[c4];
#pragma unroll
        for (int u = 0; u < 4; u++) {
#pragma unroll
            for (int l = 0; l < Lly; l++) {
                const float* w = p.Wb + (l * 32 + c4 * 4 + u) * Hh;
                a[l][0] += bv[u] * w[0]; a[l][1] += bv[u] * w[1];
                a[l][2] += bv[u] * w[2]; a[l][3] += bv[u] * w[3];
            }
        }
    }
    size_t hs = (size_t)Ssz * Ssz;
#pragma unroll
    for (int l = 0; l < Lly; l++) {
        size_t base = (((size_t)(l * Bsz + b) * Hh) * Ssz + i) * Ssz + j;
        p.Bp[base] = a[l][0]; p.Bp[base + hs] = a[l][1];
        p.Bp[base + 2 * hs] = a[l][2]; p.Bp[base + 3 * hs] = a[l][3];
    }
}

// ---- precompute E[t,row,:] for ALL cycles.  grid 8*60=480, 512 thr, 32 rows ----
__global__ __launch_bounds__(512) void k_embed_all(KParams p) {
    __shared__ float h[32][Dm], hn[32][Dm], t1[32][Dm];
    int t = blockIdx.x / 60, tile = blockIdx.x % 60;
    int row0 = tile * 32;
    int tid = threadIdx.x;
    int cid = p.cycle_ids[t];
    for (int idx = tid; idx < 32 * Dm; idx += 512) {
        int r = idx >> 7, j = idx & 127;
        int row = row0 + r;
        int b = row / Ssz, s = row % Ssz;
        int sid = p.stab_ids[s];
        int mi = (b * Tcy + t) * Ssz + s;
        h[r][j] = p.meas[mi] * p.pm_w[j] + p.pm_b[j]
                + p.event_[mi] * p.pe_w[j] + p.pe_b[j]
                + p.leak[mi] * p.pl_w[j] + p.pl_b[j]
                + p.event_leak[mi] * p.pel_w[j] + p.pel_b[j]
                + p.stab_emb[sid * Dm + j] + p.cyc_emb[cid * Dm + j];
    }
    __syncthreads();
    int g2 = tid >> 7, j = tid & 127;     // rows 8*g2 .. 8*g2+7
    for (int rbk = 0; rbk < 2; rbk++) {
        ln32(h, hn, p.er_ln_s + rbk * Dm, p.er_ln_b + rbk * Dm, tid);
        __syncthreads();
        const float* W1 = p.er_fc1_w + rbk * Dm * Dm;
        float acc[8];
#pragma unroll
        for (int rr = 0; rr < 8; rr++) acc[rr] = 0.f;
#pragma unroll 2
        for (int i4 = 0; i4 < 32; i4++) {
            float4 xv[8];
#pragma unroll
            for (int rr = 0; rr < 8; rr++) xv[rr] = *(const float4*)&hn[8 * g2 + rr][i4 * 4];
#pragma unroll
            for (int u = 0; u < 4; u++) {
                float w = W1[(i4 * 4 + u) * Dm + j];
#pragma unroll
                for (int rr = 0; rr < 8; rr++) acc[rr] += ((const float*)&xv[rr])[u] * w;
            }
        }
        float b1 = p.er_fc1_b[rbk * Dm + j];
#pragma unroll
        for (int rr = 0; rr < 8; rr++) t1[8 * g2 + rr][j] = gelu_f(acc[rr] + b1);
        __syncthreads();
        const float* W2 = p.er_fc2_w + rbk * Dm * Dm;
#pragma unroll
        for (int rr = 0; rr < 8; rr++) acc[rr] = 0.f;
#pragma unroll 2
        for (int i4 = 0; i4 < 32; i4++) {
            float4 xv[8];
#pragma unroll
            for (int rr = 0; rr < 8; rr++) xv[rr] = *(const float4*)&t1[8 * g2 + rr][i4 * 4];
#pragma unroll
            for (int u = 0; u < 4; u++) {
                float w = W2[(i4 * 4 + u) * Dm + j];
#pragma unroll
                for (int rr = 0; rr < 8; rr++) acc[rr] += ((const float*)&xv[rr])[u] * w;
            }
        }
        float b2 = p.er_fc2_b[rbk * Dm + j];
#pragma unroll
        for (int rr = 0; rr < 8; rr++) h[8 * g2 + rr][j] += acc[rr] + b2;
        __syncthreads();
    }
    for (int idx = tid; idx < 32 * Dm; idx += 512) {
        int r = idx >> 7, jj = idx & 127;
        p.E[((size_t)t * NROW + row0 + r) * Dm + jj] = h[r][jj];
    }
}

// ---- phase A: [conv(prev step) if doConv] + [X=(X+E)/sqrt2 if l==0] + ln1 + QKV
//      grid 240, 512 thr.  Q,K layout [b][h][s][e]; V TRANSPOSED [b][h][e][s] ----
__global__ __launch_bounds__(512) void k_a(KParams p, const float* Xprev, float* Xcur,
                                           int l, int t, int doConv) {
    __shared__ float xr[RT + 2][Dm];
    __shared__ float xn[RT][Dm];
    int rb = swz16(blockIdx.x, Ssz / RT);
    int row0 = rb * RT;
    int b = row0 / Ssz, s0 = row0 % Ssz;
    int tid = threadIdx.x;
    const float inv = 0.70710678118654752f;
    int g2 = tid >> 7, j = tid & 127;      // rows 2*g2, 2*g2+1

    if (doConv) {
        int lconv = l ^ 1;
        {
            float4* xr4 = (float4*)&xr[0][0];
            for (int i = tid; i < (RT + 2) * Dm / 4; i += 512) {
                int rr = i >> 5, c = i & 31;
                int s = s0 + rr - 1;
                float4 v = make_float4(0.f, 0.f, 0.f, 0.f);
                if (s >= 0 && s < Ssz) v = *(const float4*)(Xprev + (b * Ssz + s) * Dm + 4 * c);
                xr4[i] = v;
            }
        }
        __syncthreads();
        const float* CW = p.cwT + (size_t)lconv * Dm * 3 * Dm + j;
        float a0 = 0.f, a1 = 0.f;
#pragma unroll 2
        for (int i4 = 0; i4 < 32; i4++) {
            float4 xv[4];
#pragma unroll
            for (int rr = 0; rr < 4; rr++) xv[rr] = *(const float4*)&xr[2 * g2 + rr][i4 * 4];
#pragma unroll
            for (int u = 0; u < 4; u++) {
                int i = i4 * 4 + u;
                float w0 = CW[(i * 3 + 0) * Dm];
                float w1 = CW[(i * 3 + 1) * Dm];
                float w2 = CW[(i * 3 + 2) * Dm];
                a0 += w0 * ((const float*)&xv[0])[u] + w1 * ((const float*)&xv[1])[u] + w2 * ((const float*)&xv[2])[u];
                a1 += w0 * ((const float*)&xv[1])[u] + w1 * ((const float*)&xv[2])[u] + w2 * ((const float*)&xv[3])[u];
            }
        }
        float cb = p.conv_b[lconv * Dm + j];
        float v0 = xr[2 * g2 + 1][j] + gelu_f(a0 + cb);
        float v1 = xr[2 * g2 + 2][j] + gelu_f(a1 + cb);
        if (l == 0) {
            v0 = (v0 + p.E[((size_t)t * NROW + row0 + 2 * g2) * Dm + j]) * inv;
            v1 = (v1 + p.E[((size_t)t * NROW + row0 + 2 * g2 + 1) * Dm + j]) * inv;
        }
        Xcur[(row0 + 2 * g2) * Dm + j]     = v0;
        Xcur[(row0 + 2 * g2 + 1) * Dm + j] = v1;
        xn[2 * g2][j] = v0; xn[2 * g2 + 1][j] = v1;
    } else {
        // step 0: X starts at zero; X = (0 + E[0])/sqrt2
        float v0 = p.E[(size_t)(row0 + 2 * g2) * Dm + j] * inv;
        float v1 = p.E[(size_t)(row0 + 2 * g2 + 1) * Dm + j] * inv;
        Xcur[(row0 + 2 * g2) * Dm + j]     = v0;
        Xcur[(row0 + 2 * g2 + 1) * Dm + j] = v1;
        xn[2 * g2][j] = v0; xn[2 * g2 + 1][j] = v1;
    }
    __syncthreads();
    ln_rows8(xn, xn, p.ln1_s + l * Dm, p.ln1_b + l * Dm, tid);
    __syncthreads();
    if (tid < 384) {
        int out = tid >> 7, col = tid & 127;     // out: 0=Q 1=K 2=V
        int h = col >> 5, e = col & 31;
        const float* W = (out == 0 ? p.Wq : out == 1 ? p.Wk : p.Wv)
                       + ((size_t)(l * Hh + h) * Dm) * DA + e;
        const float* bbp = (out == 0 ? p.bq : out == 1 ? p.bk : p.bv) + (l * Hh + h) * DA + e;
        float acc[8];
#pragma unroll
        for (int rr = 0; rr < 8; rr++) acc[rr] = 0.f;
#pragma unroll 2
        for (int i4 = 0; i4 < 32; i4++) {
            float4 xv[8];
#pragma unroll
            for (int rr = 0; rr < 8; rr++) xv[rr] = *(const float4*)&xn[rr][i4 * 4];
#pragma unroll
            for (int u = 0; u < 4; u++) {
                float w = W[(i4 * 4 + u) * DA];
#pragma unroll
                for (int rr = 0; rr < 8; rr++) acc[rr] += ((const float*)&xv[rr])[u] * w;
            }
        }
        float bv = bbp[0];
        if (out == 2) {
            float* vb = p.V + ((size_t)(b * Hh + h) * DA + e) * Ssz + s0;
            *(float4*)vb       = make_float4(acc[0] + bv, acc[1] + bv, acc[2] + bv, acc[3] + bv);
            *(float4*)(vb + 4) = make_float4(acc[4] + bv, acc[5] + bv, acc[6] + bv, acc[7] + bv);
        } else {
            float* dst = (out == 0 ? p.Q : p.K);
            size_t base = ((size_t)(b * Hh + h) * Ssz + s0) * DA + e;
#pragma unroll
            for (int rr = 0; rr < 8; rr++) dst[base + rr * DA] = acc[rr] + bv;
        }
    }
}

// LDS overlay types for k_b (attn and ffn phases never overlap in time)
struct AttnBufs {
    float4 Kh4[Ssz][8];      // swizzled: e4 stored at slot e4^(k&7)
    float4 Vt4[DA][32];      // V^T per head, swizzled: k4 at slot k4^(e&7)
    float sc[RT][Ssz];
    float pvp[2][RT][DA];
};
struct FfnBufs {
    float opW[2][RT][Dm];
    float xres[RT][Dm];
    float xn[RT][Dm];
    float yfg[RT][256];
    float yg[RT][256];
};

// ---- phase B: attention + O-proj + ln2 + gated FFN (X in place).  grid 240, 512 thr ----
__global__ __launch_bounds__(512) void k_b(KParams p, float* X, int l) {
    __shared__ union UB { AttnBufs a; FfnBufs f; } u;
    __shared__ float Yt[RT][Dm];
    __shared__ float dn[RT];
    int rb = swz16(blockIdx.x, Ssz / RT);
    int b = rb / (Ssz / RT), qt = rb % (Ssz / RT);
    int q0 = qt * RT;
    int row0 = rb * RT;
    int tid = threadIdx.x;
    const float scale = 0.17677669529663689f;   // 1/sqrt(32)

    for (int h = 0; h < Hh; h++) {
        __syncthreads();
        {
            const float4* K4 = (const float4*)(p.K + ((size_t)(b * Hh + h) * Ssz) * DA);
            const float4* V4 = (const float4*)(p.V + ((size_t)(b * Hh + h) * DA) * Ssz);
            for (int i = tid; i < 960; i += 512) {
                int k = i >> 3, f = i & 7;
                u.a.Kh4[k][f ^ (k & 7)] = K4[i];
                int e = i / 30, s4 = i % 30;
                u.a.Vt4[e][s4 ^ (e & 7)] = V4[i];
            }
        }
        __syncthreads();
        {
            int r = tid >> 6, c0 = tid & 63;
            int c1 = c0 + 64;
            bool v1 = c1 < Ssz;
            int sw = c0 & 7;
            const float* Bpr = p.Bp + (((size_t)(l * Bsz + b) * Hh + h) * Ssz + q0 + r) * Ssz;
            const float4* Q4r = (const float4*)(p.Q + ((size_t)(b * Hh + h) * Ssz + q0 + r) * DA);
            float d0 = 0.f, d1 = 0.f;
#pragma unroll
            for (int e4 = 0; e4 < 8; e4++) {
                float4 qv = Q4r[e4];                 // broadcast
                float4 k0 = u.a.Kh4[c0][e4 ^ sw];
                d0 += qv.x * k0.x + qv.y * k0.y + qv.z * k0.z + qv.w * k0.w;
                if (v1) {
                    float4 k1 = u.a.Kh4[c1][e4 ^ sw];
                    d1 += qv.x * k1.x + qv.y * k1.y + qv.z * k1.z + qv.w * k1.w;
                }
            }
            d0 = (d0 + Bpr[c0]) * scale;
            d1 = v1 ? (d1 + Bpr[c1]) * scale : -1e30f;
            float m = fmaxf(d0, d1);
#pragma unroll
            for (int off = 32; off; off >>= 1) m = fmaxf(m, __shfl_xor(m, off));
            float p0 = expf(d0 - m);
            float p1 = v1 ? expf(d1 - m) : 0.f;
            float s = p0 + p1;
#pragma unroll
            for (int off = 32; off; off >>= 1) s += __shfl_xor(s, off);
            u.a.sc[r][c0] = p0;
            if (v1) u.a.sc[r][c1] = p1;
            if (c0 == 0) dn[r] = s;
        }
        __syncthreads();
        {
            int half = tid >> 8, r = (tid >> 5) & 7, m = tid & 31;
            int sw = m & 7;
            int k40 = half * 15;
            float a = 0.f;
#pragma unroll
            for (int k4 = 0; k4 < 15; k4++) {
                float s4v[4];
                *(float4*)s4v = *(const float4*)&u.a.sc[r][(k40 + k4) * 4];   // broadcast
                float4 vv = u.a.Vt4[m][(k40 + k4) ^ sw];
                a += s4v[0] * vv.x + s4v[1] * vv.y + s4v[2] * vv.z + s4v[3] * vv.w;
            }
            u.a.pvp[half][r][m] = a;
        }
        __syncthreads();
        if (tid < 256) {
            int r = tid >> 5, m = tid & 31;
            Yt[r][h * DA + m] = (u.a.pvp[0][r][m] + u.a.pvp[1][r][m]) / dn[r];
        }
    }
    __syncthreads();
    {
        int pp = tid >> 8, g2 = (tid >> 7) & 1, j = tid & 127;
        // O-proj split-K (attn buffers dead from here; u.f region live)
        {
            const float* W = p.Wo + l * Dm * Dm + j;
            float a[4] = {0.f, 0.f, 0.f, 0.f};
            for (int k4 = pp * 16; k4 < pp * 16 + 16; k4++) {
                float4 yv[4];
#pragma unroll
                for (int rr = 0; rr < 4; rr++) yv[rr] = *(const float4*)&Yt[4 * g2 + rr][k4 * 4];
#pragma unroll
                for (int u2 = 0; u2 < 4; u2++) {
                    float w = W[(k4 * 4 + u2) * Dm];
#pragma unroll
                    for (int rr = 0; rr < 4; rr++) a[rr] += ((const float*)&yv[rr])[u2] * w;
                }
            }
#pragma unroll
            for (int rr = 0; rr < 4; rr++) u.f.opW[pp][4 * g2 + rr][j] = a[rr];
        }
        __syncthreads();
        for (int idx = tid; idx < RT * Dm; idx += 512) {
            int r = idx >> 7, j2 = idx & 127;
            float xv = X[(row0 + r) * Dm + j2] + u.f.opW[0][r][j2] + u.f.opW[1][r][j2] + p.bo[l * Dm + j2];
            u.f.xres[r][j2] = xv;
            u.f.xn[r][j2] = xv;
        }
        __syncthreads();
        ln_rows8(u.f.xn, u.f.xn, p.ln2_s + l * Dm, p.ln2_b + l * Dm, tid);
        __syncthreads();
        // f1: thread owns one of 512 cols; gate via LDS exchange
        {
            const float* W1 = p.f1_w + (size_t)l * Dm * 512 + tid;
            float acc[8];
#pragma unroll
            for (int rr = 0; rr < 8; rr++) acc[rr] = 0.f;
#pragma unroll 2
            for (int i4 = 0; i4 < 32; i4++) {
                float4 xv[8];
#pragma unroll
                for (int rr = 0; rr < 8; rr++) xv[rr] = *(const float4*)&u.f.xn[rr][i4 * 4];
#pragma unroll
                for (int u2 = 0; u2 < 4; u2++) {
                    float w = W1[(i4 * 4 + u2) * 512];
#pragma unroll
                    for (int rr = 0; rr < 8; rr++) acc[rr] += ((const float*)&xv[rr])[u2] * w;
                }
            }
            if (tid >= 256) {
#pragma unroll
                for (int rr = 0; rr < 8; rr++) u.f.yfg[rr][tid - 256] = acc[rr];
            }
            __syncthreads();
            if (tid < 256) {
                float b1a = p.f1_b[l * 512 + tid];
                float b1g = p.f1_b[l * 512 + 256 + tid];
#pragma unroll
                for (int rr = 0; rr < 8; rr++)
                    u.f.yg[rr][tid] = gelu_f(acc[rr] + b1a) * (u.f.yfg[rr][tid] + b1g);
            }
        }
        __syncthreads();
        // f2 split-K
        {
            const float* W2 = p.f2_w + (size_t)l * 256 * Dm + j;
            float a[4] = {0.f, 0.f, 0.f, 0.f};
            for (int k4 = pp * 32; k4 < pp * 32 + 32; k4++) {
                float4 yv[4];
#pragma unroll
                for (int rr = 0; rr < 4; rr++) yv[rr] = *(const float4*)&u.f.yg[4 * g2 + rr][k4 * 4];
#pragma unroll
                for (int u2 = 0; u2 < 4; u2++) {
                    float w = W2[(k4 * 4 + u2) * Dm];
#pragma unroll
                    for (int rr = 0; rr < 4; rr++) a[rr] += ((const float*)&yv[rr])[u2] * w;
                }
            }
#pragma unroll
            for (int rr = 0; rr < 4; rr++) u.f.opW[pp][4 * g2 + rr][j] = a[rr];
        }
        __syncthreads();
        for (int idx = tid; idx < RT * Dm; idx += 512) {
            int r = idx >> 7, j2 = idx & 127;
            X[(row0 + r) * Dm + j2] = u.f.xres[r][j2] + u.f.opW[0][r][j2] + u.f.opW[1][r][j2] + p.f2_b[l * Dm + j2];
        }
    }
}

// ---- standalone conv (final step only).  grid 240, 256 thr ----
__global__ __launch_bounds__(256) void k_conv(KParams p, const float* Xin, float* Xout, int l) {
    __shared__ float xr[RT + 2][Dm];
    int rb = swz16(blockIdx.x, Ssz / RT);
    int row0 = rb * RT;
    int b = row0 / Ssz, s0 = row0 % Ssz;
    int tid = threadIdx.x;
    {
        float4* xr4 = (float4*)&xr[0][0];
        for (int i = tid; i < (RT + 2) * Dm / 4; i += 256) {
            int rr = i >> 5, c = i & 31;
            int s = s0 + rr - 1;
            float4 v = make_float4(0.f, 0.f, 0.f, 0.f);
            if (s >= 0 && s < Ssz) v = *(const float4*)(Xin + (b * Ssz + s) * Dm + 4 * c);
            xr4[i] = v;
        }
    }
    __syncthreads();
    int g = tid >> 7, j = tid & 127;      // rows 4g..4g+3
    const float* CW = p.cwT + (size_t)l * Dm * 3 * Dm + j;
    float a[4] = {0.f, 0.f, 0.f, 0.f};
#pragma unroll 2
    for (int i4 = 0; i4 < 32; i4++) {
        float4 xv[6];
#pragma unroll
        for (int rr = 0; rr < 6; rr++) xv[rr] = *(const float4*)&xr[4 * g + rr][i4 * 4];
#pragma unroll
        for (int u = 0; u < 4; u++) {
            int i = i4 * 4 + u;
            float w0 = CW[(i * 3 + 0) * Dm];
            float w1 = CW[(i * 3 + 1) * Dm];
            float w2 = CW[(i * 3 + 2) * Dm];
#pragma unroll
            for (int rr = 0; rr < 4; rr++)
                a[rr] += w0 * ((const float*)&xv[rr])[u]
                       + w1 * ((const float*)&xv[rr + 1])[u]
                       + w2 * ((const float*)&xv[rr + 2])[u];
        }
    }
    float cb = p.conv_b[l * Dm + j];
#pragma unroll
    for (int rr = 0; rr < 4; rr++)
        Xout[(row0 + 4 * g + rr) * Dm + j] = xr[4 * g + rr + 1][j] + gelu_f(a[rr] + cb);
}

// ---- fused readout: lnf (inline) + scale-conv + gelu + dim-reduce.  grid 576, 128 thr ----
__global__ __launch_bounds__(128) void k_head(KParams p, const float* X) {
    int blk = swz16(blockIdx.x, 36);
    int b = blk / 36, r2 = blk % 36, oh = r2 / 6, ow = r2 % 6;
    __shared__ float cells[4][Dm];
    __shared__ float sx[Dm];
    int tid = threadIdx.x;
    {
        int c = tid >> 5, lane = tid & 31;
        int cell = (2 * oh + (c >> 1)) * 12 + (2 * ow + (c & 1));
        if (cell < Ssz) {
            const float* Xr = X + (size_t)(b * Ssz + cell) * Dm;
            float v[4];
            float s1 = 0.f;
#pragma unroll
            for (int k = 0; k < 4; k++) { v[k] = Xr[lane + 32 * k]; s1 += v[k]; }
#pragma unroll
            for (int off = 16; off; off >>= 1) s1 += __shfl_xor(s1, off);
            float m = s1 * (1.f / 128.f);
            float s2 = 0.f;
#pragma unroll
            for (int k = 0; k < 4; k++) { float d = v[k] - m; s2 += d * d; }
#pragma unroll
            for (int off = 16; off; off >>= 1) s2 += __shfl_xor(s2, off);
            float rstd = rsqrtf(s2 * (1.f / 128.f) + 1e-5f);
#pragma unroll
            for (int k = 0; k < 4; k++) {
                int jj = lane + 32 * k;
                cells[c][jj] = (v[k] - m) * rstd * p.lnf_s[jj] + p.lnf_b[jj];
            }
        } else {
#pragma unroll
            for (int k = 0; k < 4; k++) cells[c][lane + 32 * k] = p.Pp[lane + 32 * k];
        }
    }
    __syncthreads();
    int j = tid;
    float acc = p.sc_b[j];
    const float* W = p.sc_w + (size_t)j * Dm * 4;   // [o=j][i][kh][kw]
    for (int i = 0; i < Dm; i++) {
        acc += W[i * 4 + 0] * cells[0][i] + W[i * 4 + 1] * cells[1][i]
             + W[i * 4 + 2] * cells[2][i] + W[i * 4 + 3] * cells[3][i];
    }
    sx[j] = gelu_f(acc);
    __syncthreads();
    if (j < 48) {
        float a = p.dr_b[j];
        const float* w = p.dr_w + j * Dm;
        for (int i = 0; i < Dm; i++) a += sx[i] * w[i];
        p.Y2[((b * 6 + ow) * 6 + oh) * 48 + j] = gelu_f(a);
    }
}

// ---- mean over oh + 16 resblocks + out_w dot + mean over ow.  grid 16, 320 thr ----
__global__ __launch_bounds__(320) void k_rb2(KParams p, float* out) {
    int b = swz16(blockIdx.x, 1);
    __shared__ float x[6][48], t[6][48], red[6];
    int tid = threadIdx.x;
    int ow = tid / 48, j = tid % 48;
    bool act = tid < 288;
    if (act) {
        float s = 0.f;
#pragma unroll
        for (int oh = 0; oh < 6; oh++) s += p.Y2[((b * 6 + ow) * 6 + oh) * 48 + j];
        x[ow][j] = s * (1.f / 6.f);
    }
    __syncthreads();
    for (int r = 0; r < 16; r++) {
        if (act) {
            float a = p.rb1_b[r * 48 + j];
            const float* W = p.rb1_w + (size_t)r * 48 * 48 + j;
            for (int i = 0; i < 48; i++) a += x[ow][i] * W[i * 48];
            t[ow][j] = gelu_f(a);
        }
        __syncthreads();
        if (act) {
            float a = p.rb2_b[r * 48 + j];
            const float* W = p.rb2_w + (size_t)r * 48 * 48 + j;
            for (int i = 0; i < 48; i++) a += t[ow][i] * W[i * 48];
            x[ow][j] += a;
        }
        __syncthreads();
    }
    if (act) t[ow][j] = x[ow][j] * p.out_w[j];
    __syncthreads();
    if (tid < 6) {
        float s = 0.f;
        for (int i = 0; i < 48; i++) s += t[tid][i];
        red[tid] = s;
    }
    __syncthreads();
    if (tid == 0) {
        float s = 0.f;
#pragma unroll
        for (int w = 0; w < 6; w++) s += red[w];
        out[b] = s * (1.f / 6.f) + p.out_b[0];
    }
}

extern "C" void kernel_launch(void* const* d_in, const int* in_sizes, int n_in,
                              void* d_out, int out_size, void* d_ws, size_t ws_size,
                              hipStream_t stream) {
    KParams p;
    p.meas       = (const float*)d_in[0];
    p.event_     = (const float*)d_in[1];
    p.leak       = (const float*)d_in[2];
    p.event_leak = (const float*)d_in[3];
    p.bias       = (const float*)d_in[4];
    p.pm_w  = (const float*)d_in[5];  p.pm_b  = (const float*)d_in[6];
    p.pe_w  = (const float*)d_in[7];  p.pe_b  = (const float*)d_in[8];
    p.pl_w  = (const float*)d_in[9];  p.pl_b  = (const float*)d_in[10];
    p.pel_w = (const float*)d_in[11]; p.pel_b = (const float*)d_in[12];
    p.stab_emb = (const float*)d_in[13];
    p.cyc_emb  = (const float*)d_in[14];
    p.er_ln_s  = (const float*)d_in[15]; p.er_ln_b  = (const float*)d_in[16];
    p.er_fc1_w = (const float*)d_in[17]; p.er_fc1_b = (const float*)d_in[18];
    p.er_fc2_w = (const float*)d_in[19]; p.er_fc2_b = (const float*)d_in[20];
    p.ln1_s = (const float*)d_in[21]; p.ln1_b = (const float*)d_in[22];
    p.Wb = (const float*)d_in[23];
    p.Wq = (const float*)d_in[24]; p.bq = (const float*)d_in[25];
    p.Wk = (const float*)d_in[26]; p.bk = (const float*)d_in[27];
    p.Wv = (const float*)d_in[28]; p.bv = (const float*)d_in[29];
    p.Wo = (const float*)d_in[30]; p.bo = (const float*)d_in[31];
    p.ln2_s = (const float*)d_in[32]; p.ln2_b = (const float*)d_in[33];
    p.f1_w = (const float*)d_in[34]; p.f1_b = (const float*)d_in[35];
    p.f2_w = (const float*)d_in[36]; p.f2_b = (const float*)d_in[37];
    p.conv_w = (const float*)d_in[38]; p.conv_b = (const float*)d_in[39];
    p.lnf_s = (const float*)d_in[40]; p.lnf_b = (const float*)d_in[41];
    p.Pp   = (const float*)d_in[42];
    p.sc_w = (const float*)d_in[43]; p.sc_b = (const float*)d_in[44];
    p.dr_w = (const float*)d_in[45]; p.dr_b = (const float*)d_in[46];
    p.rb1_w = (const float*)d_in[47]; p.rb1_b = (const float*)d_in[48];
    p.rb2_w = (const float*)d_in[49]; p.rb2_b = (const float*)d_in[50];
    p.out_w = (const float*)d_in[51]; p.out_b = (const float*)d_in[52];
    p.stab_ids  = (const int*)d_in[53];
    p.cycle_ids = (const int*)d_in[54];

    float* ws = (float*)d_ws;
    size_t off = 0;
    const size_t BP_SZ  = (size_t)Lly * Bsz * Hh * Ssz * Ssz;   // 1,843,200
    const size_t QKV_SZ = (size_t)Bsz * Hh * Ssz * DA;          //   245,760
    const size_t X_SZ   = (size_t)Bsz * Ssz * Dm;               //   245,760
    const size_t E_SZ   = (size_t)Tcy * NROW * Dm;              // 1,966,080
    p.Bp = ws + off; off += BP_SZ;
    p.Q  = ws + off; off += QKV_SZ;
    p.K  = ws + off; off += QKV_SZ;
    p.V  = ws + off; off += QKV_SZ;      // V stored transposed [b][h][e][s]
    float* X0 = ws + off; off += X_SZ;
    float* X1 = ws + off; off += X_SZ;
    p.Y2  = ws + off; off += (size_t)Bsz * 6 * 6 * 48;
    p.cwT = ws + off; off += (size_t)Lly * Dm * 3 * Dm;
    p.E   = ws + off; off += E_SZ;

    k_prepcw<<<(Lly * Dm * 3 * Dm + 255) / 256, 256, 0, stream>>>(p);
    k_bias<<<Bsz * Ssz, 128, 0, stream>>>(p);
    k_embed_all<<<Tcy * 60, 512, 0, stream>>>(p);

    float* Xbuf[2] = {X0, X1};
    for (int step = 0; step < Tcy * Lly; step++) {
        int t = step >> 1, l = step & 1;
        float* Xcur = Xbuf[step & 1];
        const float* Xprev = (step == 0) ? X0 : Xbuf[(step + 1) & 1];
        k_a<<<NRT, 512, 0, stream>>>(p, Xprev, Xcur, l, t, step > 0 ? 1 : 0);
        k_b<<<NRT, 512, 0, stream>>>(p, Xcur, l);
    }
    // conv of the last step (step 15, l=1): X1 -> X0, then readout from X0
    k_conv<<<NRT, 256, 0, stream>>>(p, X1, X0, 1);
    k_head<<<Bsz * 36, 128, 0, stream>>>(p, X0);
    k_rb2<<<Bsz, 320, 0, stream>>>(p, (float*)d_out);
}